// Round 14
// baseline (174.992 us; speedup 1.0000x reference)
//
#include <hip/hip_runtime.h>

// CrossAttention: B=4, C=256, H=W=64, N=4096, fp32 in/out.
// ws: qf 0 (8MB), kf 8MB, vtf 16MB, wf 24MB (384KB),
//     part f16 @24MB+384KB ((nsplit-1) x 8MB, [c][n] planes), ml f32 after.
// Split 0 partials (normalized f32) live in d_out itself ([b][c][n] layout).

typedef __attribute__((ext_vector_type(8))) short short8;
typedef __attribute__((ext_vector_type(4))) float f32x4;
typedef __attribute__((ext_vector_type(4))) int int4v;
typedef __attribute__((ext_vector_type(8))) _Float16 half8;

#define LOG2E 1.44269504089f

static __device__ __forceinline__ float exp2_fast(float x){ return __builtin_amdgcn_exp2f(x); }

static __device__ __forceinline__ int pk_f16(float a, float b){
  auto h = __builtin_amdgcn_cvt_pkrtz(a, b);   // low=a, high=b
  return __builtin_bit_cast(int, h);
}
static __device__ __forceinline__ unsigned short f2h(float v){
  return __builtin_bit_cast(unsigned short, (_Float16)v);
}

#define GLOAD16(gp, lp) __builtin_amdgcn_global_load_lds( \
  (const __attribute__((address_space(1))) void*)(gp),    \
  (__attribute__((address_space(3))) void*)(lp), 16, 0, 0)

#define MFMAF16(a,b,c) __builtin_amdgcn_mfma_f32_16x16x32_f16( \
  __builtin_bit_cast(half8, a), __builtin_bit_cast(half8, b), c, 0, 0, 0)

// ---------------------------------------------------------------- W -> f16
__global__ __launch_bounds__(256) void cvt_w(
    const float* __restrict__ wq, const float* __restrict__ wk,
    const float* __restrict__ wv, unsigned short* __restrict__ wf)
{
  const int o = blockIdx.x, t = blockIdx.y, c = threadIdx.x;
  const float* w = (t == 0) ? wq : ((t == 1) ? wk : wv);
  wf[t*65536 + o*256 + c] = f2h(w[o*256 + c]);
}

// ---------------------------------------------------------------- projections (f16 MFMA)
__global__ __launch_bounds__(256, 2) void proj_kernel(
    const float* __restrict__ x, const float* __restrict__ y,
    const unsigned short* __restrict__ wf,
    const float* __restrict__ bq, const float* __restrict__ bk, const float* __restrict__ bv,
    unsigned short* __restrict__ qf, unsigned short* __restrict__ kf,
    unsigned short* __restrict__ vtf)
{
  __shared__ float xs[256*64];       // 64KB
  __shared__ short wlds[2][4096];    // 2 x 8KB W tiles

  const int t   = blockIdx.z;
  const int b   = blockIdx.y;
  const int n0  = blockIdx.x * 64;
  const int tid = threadIdx.x;
  const int w   = tid >> 6, lane = tid & 63, g = lane >> 4, l15 = lane & 15;

  const float* src = ((t == 0) ? x : y) + (size_t)b*1048576 + n0;
  const char*  wt_b = (const char*)(wf + t*65536);

  int wsrc[2];
  #pragma unroll
  for (int i = 0; i < 2; i++){
    int s = w*2 + i;
    int row = s*2 + (lane >> 5);
    wsrc[i] = row*512 + (((lane & 31)*16) ^ ((row & 7) << 4));
  }

  #pragma unroll
  for (int i = 0; i < 16; i++){
    int c  = i*16 + (tid >> 4);
    int gg = (c >> 3) & 3;
    int sg = ((tid & 15) - 4*gg) & 15;
    GLOAD16((const char*)src + (size_t)c*16384 + sg*16,
            (char*)xs + (i*256 + tid)*16);
  }
  #pragma unroll
  for (int i = 0; i < 2; i++){
    int s = w*2 + i;
    GLOAD16(wt_b + wsrc[i], (char*)&wlds[0][0] + s*1024);
  }
  __syncthreads();

  int4v xf[8];
  {
    const int nn = (w*16 + l15 + 16*g) & 63;
    #pragma unroll
    for (int cs = 0; cs < 8; cs++){
      float v[8];
      #pragma unroll
      for (int j = 0; j < 8; j++) v[j] = xs[(cs*32 + g*8 + j)*64 + nn];
      int4v f;
      f[0] = pk_f16(v[0], v[1]); f[1] = pk_f16(v[2], v[3]);
      f[2] = pk_f16(v[4], v[5]); f[3] = pk_f16(v[6], v[7]);
      xf[cs] = f;
    }
  }

  const float* bias = (t == 0) ? bq : ((t == 1) ? bk : bv);

  int buf = 0;
  for (int ot = 0; ot < 16; ot++){
    if (ot < 15){
      #pragma unroll
      for (int i = 0; i < 2; i++){
        int s = w*2 + i;
        GLOAD16(wt_b + (ot+1)*8192 + wsrc[i], (char*)&wlds[buf^1][0] + s*1024);
      }
    }

    f32x4 acc;
    if (t < 2){
      float bo = bias[ot*16 + l15];
      acc = (f32x4){bo, bo, bo, bo};
    } else {
      acc = *(const f32x4*)&bias[ot*16 + g*4];
    }
    const char* wb = (const char*)&wlds[buf][0];
    #pragma unroll
    for (int cs = 0; cs < 8; cs++){
      short8 wfr = *(const short8*)(wb + (l15*512 + ((cs*64 + g*16) ^ ((l15 & 7) << 4))));
      if (t < 2) acc = MFMAF16(__builtin_bit_cast(short8, xf[cs]), wfr, acc);  // D[n][o]
      else       acc = MFMAF16(wfr, __builtin_bit_cast(short8, xf[cs]), acc);  // D[o][n]
    }
    if (t < 2){
      unsigned short* outp = (t == 0) ? qf : kf;
      #pragma unroll
      for (int r = 0; r < 4; r++){
        int n = n0 + w*16 + g*4 + r;
        outp[((size_t)(b*4096 + n))*256 + ot*16 + l15] = f2h(acc[r]);
      }
    } else {
      #pragma unroll
      for (int r = 0; r < 4; r++){
        int o = ot*16 + g*4 + r;
        vtf[((size_t)(b*256 + o))*4096 + n0 + w*16 + l15] = f2h(acc[r]);
      }
    }
    __syncthreads();
    buf ^= 1;
  }
}

// ---------------------------------------------------------------- attention (partials)
// 256-thr blocks (4 waves x 32 q-rows = 128 q-rows), KV stream of 4096/nsplit
// rows, KVBLK=32, 2-buf LDS (64KB) -> TWO independent blocks/CU (decorrelated
// barrier domains; same wave count, bursts interleave). Stage-after-barrier.
// Defer-max (THR=8) skips o_acc rescale on most iters; partials NORMALIZED
// (o/l) so f16 storage can't overflow.
__global__ __launch_bounds__(256, 2) void attn_kernel(
    const unsigned short* __restrict__ qf, const unsigned short* __restrict__ kf,
    const unsigned short* __restrict__ vtf,
    float* __restrict__ outp, unsigned short* __restrict__ part,
    float* __restrict__ mlbuf, int nsplit, int iters)
{
  __shared__ short k_s[2*32*256];   // [buf][m][c], rows 512B, swz ^((m&7)<<4)
  __shared__ short v_s[2*256*32];   // [buf][c][m], rows 64B,  swz ^(((c>>1)&3)<<4)

  const int tid  = threadIdx.x;
  const int w    = tid >> 6, lane = tid & 63, g = lane >> 4, col = lane & 15;
  const int bid  = blockIdx.x;

  int b, kvq, qt;
  if (nsplit == 4){
    int xcd = bid & 7, s = bid >> 3;          // s in [0,64)
    int combo = xcd*2 + (s >> 5);             // 2 (b,kvq) streams per XCD
    qt = s & 31;  b = combo >> 2;  kvq = combo & 3;
  } else {
    int combo = bid & 7;
    qt = bid >> 3;  b = combo >> 1;  kvq = combo & 1;
  }
  const int qbase = qt * 128;

  // Q fragments: nn in {0,1}; n = qbase + w*32 + nn*16 + col
  short8 qh[2][8];
  #pragma unroll
  for (int nn = 0; nn < 2; nn++){
    const size_t qoff = ((size_t)(b*4096 + qbase + w*32 + nn*16 + col))*256 + g*8;
    #pragma unroll
    for (int ch = 0; ch < 8; ch++)
      qh[nn][ch] = *(const short8*)(qf + qoff + ch*32);
  }

  f32x4 o_acc[2][16];
  #pragma unroll
  for (int nn = 0; nn < 2; nn++)
    #pragma unroll
    for (int i = 0; i < 16; i++){
      o_acc[nn][i][0]=0.f; o_acc[nn][i][1]=0.f; o_acc[nn][i][2]=0.f; o_acc[nn][i][3]=0.f;
    }
  float mst[2] = {-1e30f, -1e30f};
  float lst[2] = {0.f, 0.f};

  const int swzK = (col & 7) << 4;
  const int g16  = g << 4;
  const int kb0  = col * 512;
  const int kb1  = kb0 + 8192;
  const int vb   = col*64 + (g16 ^ (((col>>1)&3)<<4));

  const int laneA  = col + ((g & 1) ? 32 : 0);
  const int laneB  = laneA + 16;
  const bool selLow = (g < 2);

  // staging source offsets (pre-swizzled; 4 K segs + 4 V segs per wave)
  int ksrc[4], vsrc[4];
  #pragma unroll
  for (int i = 0; i < 4; i++){
    int s = w*4 + i;                      // seg in [0,16): 1KB each
    int m = s*2 + (lane >> 5);
    ksrc[i] = m*512 + (((lane & 31)*16) ^ ((m & 7) << 4));
    int c = s*16 + (lane >> 2);
    vsrc[i] = c*8192 + (((lane & 3)*16) ^ (((lane >> 3) & 3) << 4));
  }

  const int rows = 4096 / nsplit;
  const char* khg = (const char*)(kf + ((size_t)b*4096 + kvq*rows)*256);
  const char* vg  = (const char*)(vtf + ((size_t)b*256)*4096) + kvq*rows*2;

#define STAGE_TILE(T, BSEL) do {                                   \
    const char* kht_ = khg + (size_t)(T)*16384;                    \
    const char* vtt_ = vg  + (size_t)(T)*64;                       \
    const int off_ = (BSEL)*16384;                                 \
    _Pragma("unroll")                                              \
    for (int i_ = 0; i_ < 4; i_++){                                \
      int s_ = w*4 + i_;                                           \
      GLOAD16(kht_ + ksrc[i_], (char*)k_s + off_ + s_*1024);       \
      GLOAD16(vtt_ + vsrc[i_], (char*)v_s + off_ + s_*1024);       \
    }                                                              \
  } while (0)

  // prologue: stage tile 0
  STAGE_TILE(0, 0);

  for (int it = 0; it < iters; ++it){
    __syncthreads();               // drains vmcnt(0): tile it staged; old buf free

    if (it + 1 < iters)
      STAGE_TILE(it + 1, (it + 1) & 1);   // overwrites tile it-1 (safe post-barrier)

    const char* kb   = (const char*)k_s + (it & 1)*16384;
    const char* vbuf = (const char*)v_s + (it & 1)*16384;

    // ---- QK^T (swapped): K read shared by both q-frags
    f32x4 s00 = {0.f,0.f,0.f,0.f}, s01 = {0.f,0.f,0.f,0.f};
    f32x4 s10 = {0.f,0.f,0.f,0.f}, s11 = {0.f,0.f,0.f,0.f};
    __builtin_amdgcn_s_setprio(1);
    #pragma unroll
    for (int ch = 0; ch < 8; ch++){
      int inr = ((ch << 6) | g16) ^ swzK;
      short8 kh0 = *(const short8*)(kb + kb0 + inr);
      short8 kh1 = *(const short8*)(kb + kb1 + inr);
      s00 = MFMAF16(kh0, qh[0][ch], s00);
      s01 = MFMAF16(kh1, qh[0][ch], s01);
      s10 = MFMAF16(kh0, qh[1][ch], s10);
      s11 = MFMAF16(kh1, qh[1][ch], s11);
    }
    __builtin_amdgcn_s_setprio(0);

    // ---- online softmax (defer-max THR=8) + P-frag per nn
    short8 pf[2];
    #pragma unroll
    for (int nn = 0; nn < 2; nn++){
      f32x4 s0 = nn ? s10 : s00;
      f32x4 s1 = nn ? s11 : s01;
      float tmax = fmaxf(fmaxf(fmaxf(s0[0],s0[1]), fmaxf(s0[2],s0[3])),
                         fmaxf(fmaxf(s1[0],s1[1]), fmaxf(s1[2],s1[3])));
      tmax = fmaxf(tmax, __shfl_xor(tmax, 16));
      tmax = fmaxf(tmax, __shfl_xor(tmax, 32));

      if (__any(tmax > mst[nn] + 8.f)){   // defer: P <= e^8 fits f16
        float mn = fmaxf(mst[nn], tmax);
        float sc = exp2_fast((mst[nn] - mn) * LOG2E);
        lst[nn] *= sc;
        #pragma unroll
        for (int i = 0; i < 16; i++){
          o_acc[nn][i][0]*=sc; o_acc[nn][i][1]*=sc;
          o_acc[nn][i][2]*=sc; o_acc[nn][i][3]*=sc;
        }
        mst[nn] = mn;
      }
      const float mb = mst[nn] * LOG2E;
      float p0 = exp2_fast(s0[0]*LOG2E - mb);
      float p1 = exp2_fast(s0[1]*LOG2E - mb);
      float p2 = exp2_fast(s0[2]*LOG2E - mb);
      float p3 = exp2_fast(s0[3]*LOG2E - mb);
      float p4 = exp2_fast(s1[0]*LOG2E - mb);
      float p5 = exp2_fast(s1[1]*LOG2E - mb);
      float p6 = exp2_fast(s1[2]*LOG2E - mb);
      float p7 = exp2_fast(s1[3]*LOG2E - mb);

      float psum = ((p0+p1)+(p2+p3)) + ((p4+p5)+(p6+p7));
      psum += __shfl_xor(psum, 16);
      psum += __shfl_xor(psum, 32);
      lst[nn] += psum;

      int W0 = pk_f16(p0, p1);
      int W1 = pk_f16(p2, p3);
      int W2 = pk_f16(p4, p5);
      int W3 = pk_f16(p6, p7);

      int a0 = __shfl(W0, laneA), a1 = __shfl(W1, laneA);
      int a2 = __shfl(W2, laneA), a3 = __shfl(W3, laneA);
      int b0 = __shfl(W0, laneB), b1 = __shfl(W1, laneB);
      int b2 = __shfl(W2, laneB), b3 = __shfl(W3, laneB);
      int4v ti;
      ti[0] = selLow ? a0 : a2;
      ti[1] = selLow ? a1 : a3;
      ti[2] = selLow ? b0 : b2;
      ti[3] = selLow ? b1 : b3;
      pf[nn] = __builtin_bit_cast(short8, ti);   // P[n][m = g*8 + j]
    }

    // ---- PV: V read shared by both nn
    __builtin_amdgcn_s_setprio(1);
    #pragma unroll
    for (int ct = 0; ct < 16; ct++){
      short8 vf = *(const short8*)(vbuf + ct*1024 + vb);
      o_acc[0][ct] = MFMAF16(vf, pf[0], o_acc[0][ct]);
      o_acc[1][ct] = MFMAF16(vf, pf[1], o_acc[1][ct]);
    }
    __builtin_amdgcn_s_setprio(0);
  }
#undef STAGE_TILE

  // ---- epilogue: NORMALIZED partials (o/l) in output layout
  #pragma unroll
  for (int nn = 0; nn < 2; nn++){
    const int n = qbase + w*32 + nn*16 + col;
    const float rl = 1.0f / lst[nn];
    if (kvq == 0){
      #pragma unroll
      for (int ct = 0; ct < 16; ct++)
        #pragma unroll
        for (int r = 0; r < 4; r++){
          int c = ct*16 + g*4 + r;
          outp[((size_t)(b*256 + c))*4096 + n] = o_acc[nn][ct][r] * rl;
        }
    } else {
      const size_t pbase = ((size_t)((kvq-1)*1024 + b*256))*4096;
      #pragma unroll
      for (int ct = 0; ct < 16; ct++)
        #pragma unroll
        for (int r = 0; r < 4; r++){
          int c = ct*16 + g*4 + r;
          part[pbase + (size_t)c*4096 + n] = f2h(o_acc[nn][ct][r] * rl);
        }
    }
    if (g == 0){
      const size_t mb2 = ((size_t)(kvq*4 + b)*4096 + n)*2;
      mlbuf[mb2]     = mst[nn];
      mlbuf[mb2 + 1] = lst[nn];
    }
  }
}

// ---------------------------------------------------------------- merge splits
// Partials are normalized (o/l): term_s = o_s * l_s * e^{m_s - M}.
__global__ __launch_bounds__(256) void merge_kernel(
    const unsigned short* __restrict__ part, const float* __restrict__ mlbuf,
    float* __restrict__ out, int nsplit)
{
  const int T    = blockIdx.x*256 + threadIdx.x;   // 524288
  const int rowc = T >> 9;            // b*256 + c
  const int n8   = (T & 511) * 8;
  const int b    = rowc >> 8;

  float num[8], den[8], m[8];
  {
    f32x4 a0 = *(const f32x4*)&out[(size_t)rowc*4096 + n8];
    f32x4 a1 = *(const f32x4*)&out[(size_t)rowc*4096 + n8 + 4];
    const float* mlp = &mlbuf[((size_t)b*4096 + n8)*2];
    #pragma unroll
    for (int j = 0; j < 8; j++){
      m[j]   = mlp[j*2];
      den[j] = mlp[j*2 + 1];
      num[j] = ((j < 4) ? a0[j] : a1[j-4]) * den[j];
    }
  }
  for (int s = 1; s < nsplit; s++){
    short8 pv = *(const short8*)&part[((size_t)((s-1)*1024 + rowc))*4096 + n8];
    const float* mlp = &mlbuf[((size_t)(s*4 + b)*4096 + n8)*2];
    #pragma unroll
    for (int j = 0; j < 8; j++){
      float ms = mlp[j*2], ls = mlp[j*2 + 1];
      unsigned short u = (unsigned short)pv[j];
      float ps = (float)*(const _Float16*)&u;
      float mn = fmaxf(m[j], ms);
      float sa = exp2_fast((m[j] - mn) * LOG2E);
      float sb = exp2_fast((ms   - mn) * LOG2E);
      num[j] = num[j]*sa + ps*ls*sb;
      den[j] = den[j]*sa + ls*sb;
      m[j] = mn;
    }
  }
  f32x4 o0, o1;
  #pragma unroll
  for (int j = 0; j < 8; j++){
    float v = num[j] / den[j];
    if (j < 4) o0[j] = v; else o1[j-4] = v;
  }
  float* op = out + (size_t)rowc*4096 + n8;
  *(f32x4*)op       = o0;
  *(f32x4*)(op + 4) = o1;
}

// ---------------------------------------------------------------- launch
extern "C" void kernel_launch(void* const* d_in, const int* in_sizes, int n_in,
                              void* d_out, int out_size, void* d_ws, size_t ws_size,
                              hipStream_t stream)
{
  const float* x  = (const float*)d_in[0];
  const float* y  = (const float*)d_in[1];
  const float* Wq = (const float*)d_in[2];
  const float* bq = (const float*)d_in[3];
  const float* Wk = (const float*)d_in[4];
  const float* bk = (const float*)d_in[5];
  const float* Wv = (const float*)d_in[6];
  const float* bv = (const float*)d_in[7];
  float* out = (float*)d_out;

  char* ws = (char*)d_ws;
  const size_t MB = 1048576;
  unsigned short* qf   = (unsigned short*)(ws + 0*MB);
  unsigned short* kfp  = (unsigned short*)(ws + 8*MB);
  unsigned short* vtf  = (unsigned short*)(ws + 16*MB);
  unsigned short* wf   = (unsigned short*)(ws + 24*MB);
  unsigned short* part = (unsigned short*)(ws + 24*MB + 393216);

  // split 0 partials go to d_out; ws holds (nsplit-1) f16 planes + ml.
  const int nsplit = (ws_size >= 50*MB) ? 4 : 2;
  const int iters  = (4096 / nsplit) / 32;
  float* mlb = (float*)(ws + 24*MB + 393216 + (size_t)(nsplit-1)*8*MB);

  cvt_w<<<dim3(256,3), dim3(256), 0, stream>>>(Wq, Wk, Wv, wf);
  proj_kernel<<<dim3(64,4,3), dim3(256), 0, stream>>>(x, y, wf, bq, bk, bv,
                                                      qf, kfp, vtf);
  attn_kernel<<<dim3(128*nsplit), dim3(256), 0, stream>>>(qf, kfp, vtf, out, part,
                                                          mlb, nsplit, iters);
  merge_kernel<<<dim3(2048), dim3(256), 0, stream>>>(part, mlb, out, nsplit);
}

// Round 15
// 163.726 us; speedup vs baseline: 1.0688x; 1.0688x over previous
//
#include <hip/hip_runtime.h>

// CrossAttention: B=4, C=256, H=W=64, N=4096, fp32 in/out.
// ws: qf 0 (8MB), kf 8MB, vtf 16MB, wf 24MB (384KB),
//     part f16 @24MB+384KB ((nsplit-1) x 8MB, [c][n] planes), ml f32 after.
// Split 0 partials (normalized f32) live in d_out itself ([b][c][n] layout).

typedef __attribute__((ext_vector_type(8))) short short8;
typedef __attribute__((ext_vector_type(4))) float f32x4;
typedef __attribute__((ext_vector_type(4))) int int4v;
typedef __attribute__((ext_vector_type(8))) _Float16 half8;

#define LOG2E 1.44269504089f

static __device__ __forceinline__ float exp2_fast(float x){ return __builtin_amdgcn_exp2f(x); }

static __device__ __forceinline__ int pk_f16(float a, float b){
  auto h = __builtin_amdgcn_cvt_pkrtz(a, b);   // low=a, high=b
  return __builtin_bit_cast(int, h);
}
static __device__ __forceinline__ unsigned short f2h(float v){
  return __builtin_bit_cast(unsigned short, (_Float16)v);
}

#define GLOAD16(gp, lp) __builtin_amdgcn_global_load_lds( \
  (const __attribute__((address_space(1))) void*)(gp),    \
  (__attribute__((address_space(3))) void*)(lp), 16, 0, 0)

#define MFMAF16(a,b,c) __builtin_amdgcn_mfma_f32_16x16x32_f16( \
  __builtin_bit_cast(half8, a), __builtin_bit_cast(half8, b), c, 0, 0, 0)

// ---------------------------------------------------------------- W -> f16
__global__ __launch_bounds__(256) void cvt_w(
    const float* __restrict__ wq, const float* __restrict__ wk,
    const float* __restrict__ wv, unsigned short* __restrict__ wf)
{
  const int o = blockIdx.x, t = blockIdx.y, c = threadIdx.x;
  const float* w = (t == 0) ? wq : ((t == 1) ? wk : wv);
  wf[t*65536 + o*256 + c] = f2h(w[o*256 + c]);
}

// ---------------------------------------------------------------- projections (f16 MFMA)
// All 16 ot-accumulators held in registers; stores once after the loop.
// W tiles 3-buffered with raw s_barrier + counted vmcnt (no full drains).
__global__ __launch_bounds__(256, 2) void proj_kernel(
    const float* __restrict__ x, const float* __restrict__ y,
    const unsigned short* __restrict__ wf,
    const float* __restrict__ bq, const float* __restrict__ bk, const float* __restrict__ bv,
    unsigned short* __restrict__ qf, unsigned short* __restrict__ kf,
    unsigned short* __restrict__ vtf)
{
  __shared__ float xs[256*64];       // 64KB
  __shared__ short wlds[3][4096];    // 3 x 8KB W tiles

  const int t   = blockIdx.z;
  const int b   = blockIdx.y;
  const int n0  = blockIdx.x * 64;
  const int tid = threadIdx.x;
  const int w   = tid >> 6, lane = tid & 63, g = lane >> 4, l15 = lane & 15;

  const float* src = ((t == 0) ? x : y) + (size_t)b*1048576 + n0;
  const char*  wt_b = (const char*)(wf + t*65536);

  int wsrc[2];
  #pragma unroll
  for (int i = 0; i < 2; i++){
    int s = w*2 + i;
    int row = s*2 + (lane >> 5);
    wsrc[i] = row*512 + (((lane & 31)*16) ^ ((row & 7) << 4));
  }

  // prologue: x-tile (rotated rows) + W tile 0
  #pragma unroll
  for (int i = 0; i < 16; i++){
    int c  = i*16 + (tid >> 4);
    int gg = (c >> 3) & 3;
    int sg = ((tid & 15) - 4*gg) & 15;
    GLOAD16((const char*)src + (size_t)c*16384 + sg*16,
            (char*)xs + (i*256 + tid)*16);
  }
  #pragma unroll
  for (int i = 0; i < 2; i++){
    int s = w*2 + i;
    GLOAD16(wt_b + wsrc[i], (char*)&wlds[0][0] + s*1024);
  }
  __syncthreads();   // x + W0 staged (single full drain)

  // x^T fragments
  int4v xf[8];
  {
    const int nn = (w*16 + l15 + 16*g) & 63;
    #pragma unroll
    for (int cs = 0; cs < 8; cs++){
      float v[8];
      #pragma unroll
      for (int j = 0; j < 8; j++) v[j] = xs[(cs*32 + g*8 + j)*64 + nn];
      int4v f;
      f[0] = pk_f16(v[0], v[1]); f[1] = pk_f16(v[2], v[3]);
      f[2] = pk_f16(v[4], v[5]); f[3] = pk_f16(v[6], v[7]);
      xf[cs] = f;
    }
  }

  const float* bias = (t == 0) ? bq : ((t == 1) ? bk : bv);

  f32x4 acc[16];
  #pragma unroll
  for (int ot = 0; ot < 16; ot++){
    if (ot < 15){
      #pragma unroll
      for (int i = 0; i < 2; i++){
        int s = w*2 + i;
        GLOAD16(wt_b + (ot+1)*8192 + wsrc[i], (char*)&wlds[(ot+1)%3][0] + s*1024);
      }
      asm volatile("s_waitcnt vmcnt(2)" ::: "memory");   // tile ot landed
    } else {
      asm volatile("s_waitcnt vmcnt(0)" ::: "memory");
    }
    __builtin_amdgcn_s_barrier();
    __builtin_amdgcn_sched_barrier(0);

    f32x4 a;
    if (t < 2){
      float bo = bias[ot*16 + l15];
      a = (f32x4){bo, bo, bo, bo};
    } else {
      a = *(const f32x4*)&bias[ot*16 + g*4];
    }
    const char* wb = (const char*)&wlds[ot%3][0];
    #pragma unroll
    for (int cs = 0; cs < 8; cs++){
      short8 wfr = *(const short8*)(wb + (l15*512 + ((cs*64 + g*16) ^ ((l15 & 7) << 4))));
      if (t < 2) a = MFMAF16(__builtin_bit_cast(short8, xf[cs]), wfr, a);  // D[n][o]
      else       a = MFMAF16(wfr, __builtin_bit_cast(short8, xf[cs]), a);  // D[o][n]
    }
    acc[ot] = a;
  }

  // epilogue: all stores once
  if (t < 2){
    unsigned short* outp = (t == 0) ? qf : kf;
    #pragma unroll
    for (int ot = 0; ot < 16; ot++)
      #pragma unroll
      for (int r = 0; r < 4; r++){
        int n = n0 + w*16 + g*4 + r;
        outp[((size_t)(b*4096 + n))*256 + ot*16 + l15] = f2h(acc[ot][r]);
      }
  } else {
    #pragma unroll
    for (int ot = 0; ot < 16; ot++)
      #pragma unroll
      for (int r = 0; r < 4; r++){
        int o = ot*16 + g*4 + r;
        vtf[((size_t)(b*256 + o))*4096 + n0 + w*16 + l15] = f2h(acc[ot][r]);
      }
  }
}

// ---------------------------------------------------------------- attention (partials)
// r10 structure (best measured: 98us): 8 waves x 32 q-rows = 256 q-rows,
// KV stream 4096/nsplit rows, KVBLK=32, TRIPLE-buffered LDS (96KB), counted
// vmcnt(4), stage-before-wait. Adds: defer-max (THR=8) and normalized f16
// partials. Split 0 -> f32 in d_out; splits >=1 -> f16 [c][n] planes.
__global__ __launch_bounds__(512, 1) void attn_kernel(
    const unsigned short* __restrict__ qf, const unsigned short* __restrict__ kf,
    const unsigned short* __restrict__ vtf,
    float* __restrict__ outp, unsigned short* __restrict__ part,
    float* __restrict__ mlbuf, int nsplit, int iters)
{
  __shared__ short k_s[3*32*256];   // [buf][m][c], rows 512B, swz ^((m&7)<<4)
  __shared__ short v_s[3*256*32];   // [buf][c][m], rows 64B,  swz ^(((c>>1)&3)<<4)

  const int tid  = threadIdx.x;
  const int w    = tid >> 6, lane = tid & 63, g = lane >> 4, col = lane & 15;
  const int bid  = blockIdx.x;

  int b, kvq, qt;
  if (nsplit == 4){
    int xcd = bid & 7, s = bid >> 3;
    int combo = xcd*2 + (s >> 4);
    qt = s & 15;  b = combo >> 2;  kvq = combo & 3;
  } else {
    int combo = bid & 7;
    qt = bid >> 3;  b = combo >> 1;  kvq = combo & 1;
  }
  const int qbase = qt * 256;

  // Q fragments: nn in {0,1}; n = qbase + w*32 + nn*16 + col
  short8 qh[2][8];
  #pragma unroll
  for (int nn = 0; nn < 2; nn++){
    const size_t qoff = ((size_t)(b*4096 + qbase + w*32 + nn*16 + col))*256 + g*8;
    #pragma unroll
    for (int ch = 0; ch < 8; ch++)
      qh[nn][ch] = *(const short8*)(qf + qoff + ch*32);
  }

  f32x4 o_acc[2][16];
  #pragma unroll
  for (int nn = 0; nn < 2; nn++)
    #pragma unroll
    for (int i = 0; i < 16; i++){
      o_acc[nn][i][0]=0.f; o_acc[nn][i][1]=0.f; o_acc[nn][i][2]=0.f; o_acc[nn][i][3]=0.f;
    }
  float mst[2] = {-1e30f, -1e30f};
  float lst[2] = {0.f, 0.f};

  const int swzK = (col & 7) << 4;
  const int g16  = g << 4;
  const int kb0  = col * 512;
  const int kb1  = kb0 + 8192;
  const int vb   = col*64 + (g16 ^ (((col>>1)&3)<<4));

  const int laneA  = col + ((g & 1) ? 32 : 0);
  const int laneB  = laneA + 16;
  const bool selLow = (g < 2);

  int ksrc[2], vsrc[2];
  #pragma unroll
  for (int i = 0; i < 2; i++){
    int s = w*2 + i;
    int m = s*2 + (lane >> 5);
    ksrc[i] = m*512 + (((lane & 31)*16) ^ ((m & 7) << 4));
    int c = s*16 + (lane >> 2);
    vsrc[i] = c*8192 + (((lane & 3)*16) ^ (((lane >> 3) & 3) << 4));
  }

  const int rows = 4096 / nsplit;
  const char* khg = (const char*)(kf + ((size_t)b*4096 + kvq*rows)*256);
  const char* vg  = (const char*)(vtf + ((size_t)b*256)*4096) + kvq*rows*2;

#define STAGE_TILE(T, BSEL) do {                                   \
    const char* kht_ = khg + (size_t)(T)*16384;                    \
    const char* vtt_ = vg  + (size_t)(T)*64;                       \
    const int off_ = (BSEL)*16384;                                 \
    _Pragma("unroll")                                              \
    for (int i_ = 0; i_ < 2; i_++){                                \
      int s_ = w*2 + i_;                                           \
      GLOAD16(kht_ + ksrc[i_], (char*)k_s + off_ + s_*1024);       \
      GLOAD16(vtt_ + vsrc[i_], (char*)v_s + off_ + s_*1024);       \
    }                                                              \
  } while (0)

  // prologue: stage tile 0 into buf 0
  STAGE_TILE(0, 0);

  int cur = 0, nxt = 1;
  for (int it = 0; it < iters; ++it){
    if (it + 1 < iters){
      STAGE_TILE(it + 1, nxt);                           // issued BEFORE wait
      asm volatile("s_waitcnt vmcnt(4)" ::: "memory");   // tile `it` landed
    } else {
      asm volatile("s_waitcnt vmcnt(0)" ::: "memory");
    }
    __builtin_amdgcn_s_barrier();
    __builtin_amdgcn_sched_barrier(0);

    const char* kb   = (const char*)k_s + cur*16384;
    const char* vbuf = (const char*)v_s + cur*16384;

    // ---- QK^T (swapped): K read shared by both q-frags
    f32x4 s00 = {0.f,0.f,0.f,0.f}, s01 = {0.f,0.f,0.f,0.f};
    f32x4 s10 = {0.f,0.f,0.f,0.f}, s11 = {0.f,0.f,0.f,0.f};
    __builtin_amdgcn_s_setprio(1);
    #pragma unroll
    for (int ch = 0; ch < 8; ch++){
      int inr = ((ch << 6) | g16) ^ swzK;
      short8 kh0 = *(const short8*)(kb + kb0 + inr);
      short8 kh1 = *(const short8*)(kb + kb1 + inr);
      s00 = MFMAF16(kh0, qh[0][ch], s00);
      s01 = MFMAF16(kh1, qh[0][ch], s01);
      s10 = MFMAF16(kh0, qh[1][ch], s10);
      s11 = MFMAF16(kh1, qh[1][ch], s11);
    }
    __builtin_amdgcn_s_setprio(0);

    // ---- online softmax (defer-max THR=8) + P-frag per nn
    short8 pf[2];
    #pragma unroll
    for (int nn = 0; nn < 2; nn++){
      f32x4 s0 = nn ? s10 : s00;
      f32x4 s1 = nn ? s11 : s01;
      float tmax = fmaxf(fmaxf(fmaxf(s0[0],s0[1]), fmaxf(s0[2],s0[3])),
                         fmaxf(fmaxf(s1[0],s1[1]), fmaxf(s1[2],s1[3])));
      tmax = fmaxf(tmax, __shfl_xor(tmax, 16));
      tmax = fmaxf(tmax, __shfl_xor(tmax, 32));

      if (__any(tmax > mst[nn] + 8.f)){   // defer: P <= e^8 fits f16/f32 fine
        float mn = fmaxf(mst[nn], tmax);
        float sc = exp2_fast((mst[nn] - mn) * LOG2E);
        lst[nn] *= sc;
        #pragma unroll
        for (int i = 0; i < 16; i++){
          o_acc[nn][i][0]*=sc; o_acc[nn][i][1]*=sc;
          o_acc[nn][i][2]*=sc; o_acc[nn][i][3]*=sc;
        }
        mst[nn] = mn;
      }
      const float mb = mst[nn] * LOG2E;
      float p0 = exp2_fast(s0[0]*LOG2E - mb);
      float p1 = exp2_fast(s0[1]*LOG2E - mb);
      float p2 = exp2_fast(s0[2]*LOG2E - mb);
      float p3 = exp2_fast(s0[3]*LOG2E - mb);
      float p4 = exp2_fast(s1[0]*LOG2E - mb);
      float p5 = exp2_fast(s1[1]*LOG2E - mb);
      float p6 = exp2_fast(s1[2]*LOG2E - mb);
      float p7 = exp2_fast(s1[3]*LOG2E - mb);

      float psum = ((p0+p1)+(p2+p3)) + ((p4+p5)+(p6+p7));
      psum += __shfl_xor(psum, 16);
      psum += __shfl_xor(psum, 32);
      lst[nn] += psum;

      int W0 = pk_f16(p0, p1);
      int W1 = pk_f16(p2, p3);
      int W2 = pk_f16(p4, p5);
      int W3 = pk_f16(p6, p7);

      int a0 = __shfl(W0, laneA), a1 = __shfl(W1, laneA);
      int a2 = __shfl(W2, laneA), a3 = __shfl(W3, laneA);
      int b0 = __shfl(W0, laneB), b1 = __shfl(W1, laneB);
      int b2 = __shfl(W2, laneB), b3 = __shfl(W3, laneB);
      int4v ti;
      ti[0] = selLow ? a0 : a2;
      ti[1] = selLow ? a1 : a3;
      ti[2] = selLow ? b0 : b2;
      ti[3] = selLow ? b1 : b3;
      pf[nn] = __builtin_bit_cast(short8, ti);   // P[n][m = g*8 + j]
    }

    // ---- PV: V read shared by both nn
    __builtin_amdgcn_s_setprio(1);
    #pragma unroll
    for (int ct = 0; ct < 16; ct++){
      short8 vf = *(const short8*)(vbuf + ct*1024 + vb);
      o_acc[0][ct] = MFMAF16(vf, pf[0], o_acc[0][ct]);
      o_acc[1][ct] = MFMAF16(vf, pf[1], o_acc[1][ct]);
    }
    __builtin_amdgcn_s_setprio(0);

    cur = nxt;
    nxt = (nxt + 1 == 3) ? 0 : nxt + 1;
  }
#undef STAGE_TILE

  // ---- epilogue: NORMALIZED partials (o/l) in output layout
  #pragma unroll
  for (int nn = 0; nn < 2; nn++){
    const int n = qbase + w*32 + nn*16 + col;
    const float rl = 1.0f / lst[nn];
    if (kvq == 0){
      #pragma unroll
      for (int ct = 0; ct < 16; ct++)
        #pragma unroll
        for (int r = 0; r < 4; r++){
          int c = ct*16 + g*4 + r;
          outp[((size_t)(b*256 + c))*4096 + n] = o_acc[nn][ct][r] * rl;
        }
    } else {
      const size_t pbase = ((size_t)((kvq-1)*1024 + b*256))*4096;
      #pragma unroll
      for (int ct = 0; ct < 16; ct++)
        #pragma unroll
        for (int r = 0; r < 4; r++){
          int c = ct*16 + g*4 + r;
          part[pbase + (size_t)c*4096 + n] = f2h(o_acc[nn][ct][r] * rl);
        }
    }
    if (g == 0){
      const size_t mb2 = ((size_t)(kvq*4 + b)*4096 + n)*2;
      mlbuf[mb2]     = mst[nn];
      mlbuf[mb2 + 1] = lst[nn];
    }
  }
}

// ---------------------------------------------------------------- merge splits
// Partials are normalized (o/l): term_s = o_s * l_s * e^{m_s - M}.
__global__ __launch_bounds__(256) void merge_kernel(
    const unsigned short* __restrict__ part, const float* __restrict__ mlbuf,
    float* __restrict__ out, int nsplit)
{
  const int T    = blockIdx.x*256 + threadIdx.x;   // 524288
  const int rowc = T >> 9;            // b*256 + c
  const int n8   = (T & 511) * 8;
  const int b    = rowc >> 8;

  float num[8], den[8], m[8];
  {
    f32x4 a0 = *(const f32x4*)&out[(size_t)rowc*4096 + n8];
    f32x4 a1 = *(const f32x4*)&out[(size_t)rowc*4096 + n8 + 4];
    const float* mlp = &mlbuf[((size_t)b*4096 + n8)*2];
    #pragma unroll
    for (int j = 0; j < 8; j++){
      m[j]   = mlp[j*2];
      den[j] = mlp[j*2 + 1];
      num[j] = ((j < 4) ? a0[j] : a1[j-4]) * den[j];
    }
  }
  for (int s = 1; s < nsplit; s++){
    short8 pv = *(const short8*)&part[((size_t)((s-1)*1024 + rowc))*4096 + n8];
    const float* mlp = &mlbuf[((size_t)(s*4 + b)*4096 + n8)*2];
    #pragma unroll
    for (int j = 0; j < 8; j++){
      float ms = mlp[j*2], ls = mlp[j*2 + 1];
      unsigned short u = (unsigned short)pv[j];
      float ps = (float)*(const _Float16*)&u;
      float mn = fmaxf(m[j], ms);
      float sa = exp2_fast((m[j] - mn) * LOG2E);
      float sb = exp2_fast((ms   - mn) * LOG2E);
      num[j] = num[j]*sa + ps*ls*sb;
      den[j] = den[j]*sa + ls*sb;
      m[j] = mn;
    }
  }
  f32x4 o0, o1;
  #pragma unroll
  for (int j = 0; j < 8; j++){
    float v = num[j] / den[j];
    if (j < 4) o0[j] = v; else o1[j-4] = v;
  }
  float* op = out + (size_t)rowc*4096 + n8;
  *(f32x4*)op       = o0;
  *(f32x4*)(op + 4) = o1;
}

// ---------------------------------------------------------------- launch
extern "C" void kernel_launch(void* const* d_in, const int* in_sizes, int n_in,
                              void* d_out, int out_size, void* d_ws, size_t ws_size,
                              hipStream_t stream)
{
  const float* x  = (const float*)d_in[0];
  const float* y  = (const float*)d_in[1];
  const float* Wq = (const float*)d_in[2];
  const float* bq = (const float*)d_in[3];
  const float* Wk = (const float*)d_in[4];
  const float* bk = (const float*)d_in[5];
  const float* Wv = (const float*)d_in[6];
  const float* bv = (const float*)d_in[7];
  float* out = (float*)d_out;

  char* ws = (char*)d_ws;
  const size_t MB = 1048576;
  unsigned short* qf   = (unsigned short*)(ws + 0*MB);
  unsigned short* kfp  = (unsigned short*)(ws + 8*MB);
  unsigned short* vtf  = (unsigned short*)(ws + 16*MB);
  unsigned short* wf   = (unsigned short*)(ws + 24*MB);
  unsigned short* part = (unsigned short*)(ws + 24*MB + 393216);

  // split 0 partials go to d_out; ws holds (nsplit-1) f16 planes + ml.
  const int nsplit = (ws_size >= 50*MB) ? 4 : 2;
  const int iters  = (4096 / nsplit) / 32;
  float* mlb = (float*)(ws + 24*MB + 393216 + (size_t)(nsplit-1)*8*MB);

  cvt_w<<<dim3(256,3), dim3(256), 0, stream>>>(Wq, Wk, Wv, wf);
  proj_kernel<<<dim3(64,4,3), dim3(256), 0, stream>>>(x, y, wf, bq, bk, bv,
                                                      qf, kfp, vtf);
  attn_kernel<<<dim3(64*nsplit), dim3(512), 0, stream>>>(qf, kfp, vtf, out, part,
                                                         mlb, nsplit, iters);
  merge_kernel<<<dim3(2048), dim3(256), 0, stream>>>(part, mlb, out, nsplit);
}

// Round 16
// 154.375 us; speedup vs baseline: 1.1336x; 1.0606x over previous
//
#include <hip/hip_runtime.h>

// CrossAttention: B=4, C=256, H=W=64, N=4096, fp32 in/out.
// ws: qf 0 (8MB), kf 8MB, vtf 16MB, wf 24MB (384KB),
//     part f16 @24MB+384KB ((nsplit-1) x 8MB, [c][n] planes), ml f32 after.
// Split 0 partials (normalized f32) live in d_out itself ([b][c][n] layout).

typedef __attribute__((ext_vector_type(8))) short short8;
typedef __attribute__((ext_vector_type(4))) float f32x4;
typedef __attribute__((ext_vector_type(4))) int int4v;
typedef __attribute__((ext_vector_type(8))) _Float16 half8;

#define LOG2E 1.44269504089f

static __device__ __forceinline__ float exp2_fast(float x){ return __builtin_amdgcn_exp2f(x); }

static __device__ __forceinline__ int pk_f16(float a, float b){
  auto h = __builtin_amdgcn_cvt_pkrtz(a, b);   // low=a, high=b
  return __builtin_bit_cast(int, h);
}
static __device__ __forceinline__ unsigned short f2h(float v){
  return __builtin_bit_cast(unsigned short, (_Float16)v);
}

#define GLOAD16(gp, lp) __builtin_amdgcn_global_load_lds( \
  (const __attribute__((address_space(1))) void*)(gp),    \
  (__attribute__((address_space(3))) void*)(lp), 16, 0, 0)

#define MFMAF16(a,b,c) __builtin_amdgcn_mfma_f32_16x16x32_f16( \
  __builtin_bit_cast(half8, a), __builtin_bit_cast(half8, b), c, 0, 0, 0)

// ---------------------------------------------------------------- W -> f16
__global__ __launch_bounds__(256) void cvt_w(
    const float* __restrict__ wq, const float* __restrict__ wk,
    const float* __restrict__ wv, unsigned short* __restrict__ wf)
{
  const int o = blockIdx.x, t = blockIdx.y, c = threadIdx.x;
  const float* w = (t == 0) ? wq : ((t == 1) ? wk : wv);
  wf[t*65536 + o*256 + c] = f2h(w[o*256 + c]);
}

// ---------------------------------------------------------------- projections (f16 MFMA)
// 2-buf W tiles (LDS 80KB -> 2 blocks/CU; r15's 3-buf 88KB halved occupancy).
// All 16 ot-accumulators in registers; stores once after the loop.
__global__ __launch_bounds__(256, 2) void proj_kernel(
    const float* __restrict__ x, const float* __restrict__ y,
    const unsigned short* __restrict__ wf,
    const float* __restrict__ bq, const float* __restrict__ bk, const float* __restrict__ bv,
    unsigned short* __restrict__ qf, unsigned short* __restrict__ kf,
    unsigned short* __restrict__ vtf)
{
  __shared__ float xs[256*64];       // 64KB
  __shared__ short wlds[2][4096];    // 2 x 8KB W tiles

  const int t   = blockIdx.z;
  const int b   = blockIdx.y;
  const int n0  = blockIdx.x * 64;
  const int tid = threadIdx.x;
  const int w   = tid >> 6, lane = tid & 63, g = lane >> 4, l15 = lane & 15;

  const float* src = ((t == 0) ? x : y) + (size_t)b*1048576 + n0;
  const char*  wt_b = (const char*)(wf + t*65536);

  int wsrc[2];
  #pragma unroll
  for (int i = 0; i < 2; i++){
    int s = w*2 + i;
    int row = s*2 + (lane >> 5);
    wsrc[i] = row*512 + (((lane & 31)*16) ^ ((row & 7) << 4));
  }

  // prologue: x-tile (rotated rows) + W tile 0
  #pragma unroll
  for (int i = 0; i < 16; i++){
    int c  = i*16 + (tid >> 4);
    int gg = (c >> 3) & 3;
    int sg = ((tid & 15) - 4*gg) & 15;
    GLOAD16((const char*)src + (size_t)c*16384 + sg*16,
            (char*)xs + (i*256 + tid)*16);
  }
  #pragma unroll
  for (int i = 0; i < 2; i++){
    int s = w*2 + i;
    GLOAD16(wt_b + wsrc[i], (char*)&wlds[0][0] + s*1024);
  }
  __syncthreads();   // x + W0 staged

  // x^T fragments
  int4v xf[8];
  {
    const int nn = (w*16 + l15 + 16*g) & 63;
    #pragma unroll
    for (int cs = 0; cs < 8; cs++){
      float v[8];
      #pragma unroll
      for (int j = 0; j < 8; j++) v[j] = xs[(cs*32 + g*8 + j)*64 + nn];
      int4v f;
      f[0] = pk_f16(v[0], v[1]); f[1] = pk_f16(v[2], v[3]);
      f[2] = pk_f16(v[4], v[5]); f[3] = pk_f16(v[6], v[7]);
      xf[cs] = f;
    }
  }

  const float* bias = (t == 0) ? bq : ((t == 1) ? bk : bv);

  f32x4 acc[16];
  int buf = 0;
  #pragma unroll
  for (int ot = 0; ot < 16; ot++){
    if (ot < 15){   // stage next W tile into buf^1 (last read at ot-1; safe post-barrier)
      #pragma unroll
      for (int i = 0; i < 2; i++){
        int s = w*2 + i;
        GLOAD16(wt_b + (ot+1)*8192 + wsrc[i], (char*)&wlds[buf^1][0] + s*1024);
      }
    }

    f32x4 a;
    if (t < 2){
      float bo = bias[ot*16 + l15];
      a = (f32x4){bo, bo, bo, bo};
    } else {
      a = *(const f32x4*)&bias[ot*16 + g*4];
    }
    const char* wb = (const char*)&wlds[buf][0];
    #pragma unroll
    for (int cs = 0; cs < 8; cs++){
      short8 wfr = *(const short8*)(wb + (l15*512 + ((cs*64 + g*16) ^ ((l15 & 7) << 4))));
      if (t < 2) a = MFMAF16(__builtin_bit_cast(short8, xf[cs]), wfr, a);  // D[n][o]
      else       a = MFMAF16(wfr, __builtin_bit_cast(short8, xf[cs]), a);  // D[o][n]
    }
    acc[ot] = a;

    __syncthreads();   // drains stage (vmcnt 0) + all reads of wlds[buf] done
    buf ^= 1;
  }

  // epilogue: all stores once
  if (t < 2){
    unsigned short* outp = (t == 0) ? qf : kf;
    #pragma unroll
    for (int ot = 0; ot < 16; ot++)
      #pragma unroll
      for (int r = 0; r < 4; r++){
        int n = n0 + w*16 + g*4 + r;
        outp[((size_t)(b*4096 + n))*256 + ot*16 + l15] = f2h(acc[ot][r]);
      }
  } else {
    #pragma unroll
    for (int ot = 0; ot < 16; ot++)
      #pragma unroll
      for (int r = 0; r < 4; r++){
        int o = ot*16 + g*4 + r;
        vtf[((size_t)(b*256 + o))*4096 + n0 + w*16 + l15] = f2h(acc[ot][r]);
      }
  }
}

// ---------------------------------------------------------------- attention (partials)
// r10 structure (best measured): 8 waves x 32 q-rows = 256 q-rows, KV stream
// 4096/nsplit rows, KVBLK=32, TRIPLE-buffered LDS (96KB), counted vmcnt(4),
// stage-before-wait. Defer-max (THR=8); normalized f16 partials.
__global__ __launch_bounds__(512, 1) void attn_kernel(
    const unsigned short* __restrict__ qf, const unsigned short* __restrict__ kf,
    const unsigned short* __restrict__ vtf,
    float* __restrict__ outp, unsigned short* __restrict__ part,
    float* __restrict__ mlbuf, int nsplit, int iters)
{
  __shared__ short k_s[3*32*256];   // [buf][m][c], rows 512B, swz ^((m&7)<<4)
  __shared__ short v_s[3*256*32];   // [buf][c][m], rows 64B,  swz ^(((c>>1)&3)<<4)

  const int tid  = threadIdx.x;
  const int w    = tid >> 6, lane = tid & 63, g = lane >> 4, col = lane & 15;
  const int bid  = blockIdx.x;

  int b, kvq, qt;
  if (nsplit == 4){
    int xcd = bid & 7, s = bid >> 3;
    int combo = xcd*2 + (s >> 4);
    qt = s & 15;  b = combo >> 2;  kvq = combo & 3;
  } else {
    int combo = bid & 7;
    qt = bid >> 3;  b = combo >> 1;  kvq = combo & 1;
  }
  const int qbase = qt * 256;

  // Q fragments: nn in {0,1}; n = qbase + w*32 + nn*16 + col
  short8 qh[2][8];
  #pragma unroll
  for (int nn = 0; nn < 2; nn++){
    const size_t qoff = ((size_t)(b*4096 + qbase + w*32 + nn*16 + col))*256 + g*8;
    #pragma unroll
    for (int ch = 0; ch < 8; ch++)
      qh[nn][ch] = *(const short8*)(qf + qoff + ch*32);
  }

  f32x4 o_acc[2][16];
  #pragma unroll
  for (int nn = 0; nn < 2; nn++)
    #pragma unroll
    for (int i = 0; i < 16; i++){
      o_acc[nn][i][0]=0.f; o_acc[nn][i][1]=0.f; o_acc[nn][i][2]=0.f; o_acc[nn][i][3]=0.f;
    }
  float mst[2] = {-1e30f, -1e30f};
  float lst[2] = {0.f, 0.f};

  const int swzK = (col & 7) << 4;
  const int g16  = g << 4;
  const int kb0  = col * 512;
  const int kb1  = kb0 + 8192;
  const int vb   = col*64 + (g16 ^ (((col>>1)&3)<<4));

  const int laneA  = col + ((g & 1) ? 32 : 0);
  const int laneB  = laneA + 16;
  const bool selLow = (g < 2);

  int ksrc[2], vsrc[2];
  #pragma unroll
  for (int i = 0; i < 2; i++){
    int s = w*2 + i;
    int m = s*2 + (lane >> 5);
    ksrc[i] = m*512 + (((lane & 31)*16) ^ ((m & 7) << 4));
    int c = s*16 + (lane >> 2);
    vsrc[i] = c*8192 + (((lane & 3)*16) ^ (((lane >> 3) & 3) << 4));
  }

  const int rows = 4096 / nsplit;
  const char* khg = (const char*)(kf + ((size_t)b*4096 + kvq*rows)*256);
  const char* vg  = (const char*)(vtf + ((size_t)b*256)*4096) + kvq*rows*2;

#define STAGE_TILE(T, BSEL) do {                                   \
    const char* kht_ = khg + (size_t)(T)*16384;                    \
    const char* vtt_ = vg  + (size_t)(T)*64;                       \
    const int off_ = (BSEL)*16384;                                 \
    _Pragma("unroll")                                              \
    for (int i_ = 0; i_ < 2; i_++){                                \
      int s_ = w*2 + i_;                                           \
      GLOAD16(kht_ + ksrc[i_], (char*)k_s + off_ + s_*1024);       \
      GLOAD16(vtt_ + vsrc[i_], (char*)v_s + off_ + s_*1024);       \
    }                                                              \
  } while (0)

  // prologue: stage tile 0 into buf 0
  STAGE_TILE(0, 0);

  int cur = 0, nxt = 1;
  for (int it = 0; it < iters; ++it){
    if (it + 1 < iters){
      STAGE_TILE(it + 1, nxt);                           // issued BEFORE wait
      asm volatile("s_waitcnt vmcnt(4)" ::: "memory");   // tile `it` landed
    } else {
      asm volatile("s_waitcnt vmcnt(0)" ::: "memory");
    }
    __builtin_amdgcn_s_barrier();
    __builtin_amdgcn_sched_barrier(0);

    const char* kb   = (const char*)k_s + cur*16384;
    const char* vbuf = (const char*)v_s + cur*16384;

    // ---- QK^T (swapped): K read shared by both q-frags
    f32x4 s00 = {0.f,0.f,0.f,0.f}, s01 = {0.f,0.f,0.f,0.f};
    f32x4 s10 = {0.f,0.f,0.f,0.f}, s11 = {0.f,0.f,0.f,0.f};
    __builtin_amdgcn_s_setprio(1);
    #pragma unroll
    for (int ch = 0; ch < 8; ch++){
      int inr = ((ch << 6) | g16) ^ swzK;
      short8 kh0 = *(const short8*)(kb + kb0 + inr);
      short8 kh1 = *(const short8*)(kb + kb1 + inr);
      s00 = MFMAF16(kh0, qh[0][ch], s00);
      s01 = MFMAF16(kh1, qh[0][ch], s01);
      s10 = MFMAF16(kh0, qh[1][ch], s10);
      s11 = MFMAF16(kh1, qh[1][ch], s11);
    }
    __builtin_amdgcn_s_setprio(0);

    // ---- online softmax (defer-max THR=8) + P-frag per nn
    short8 pf[2];
    #pragma unroll
    for (int nn = 0; nn < 2; nn++){
      f32x4 s0 = nn ? s10 : s00;
      f32x4 s1 = nn ? s11 : s01;
      float tmax = fmaxf(fmaxf(fmaxf(s0[0],s0[1]), fmaxf(s0[2],s0[3])),
                         fmaxf(fmaxf(s1[0],s1[1]), fmaxf(s1[2],s1[3])));
      tmax = fmaxf(tmax, __shfl_xor(tmax, 16));
      tmax = fmaxf(tmax, __shfl_xor(tmax, 32));

      if (__any(tmax > mst[nn] + 8.f)){   // defer: P <= e^8, f16-safe
        float mn = fmaxf(mst[nn], tmax);
        float sc = exp2_fast((mst[nn] - mn) * LOG2E);
        lst[nn] *= sc;
        #pragma unroll
        for (int i = 0; i < 16; i++){
          o_acc[nn][i][0]*=sc; o_acc[nn][i][1]*=sc;
          o_acc[nn][i][2]*=sc; o_acc[nn][i][3]*=sc;
        }
        mst[nn] = mn;
      }
      const float mb = mst[nn] * LOG2E;
      float p0 = exp2_fast(s0[0]*LOG2E - mb);
      float p1 = exp2_fast(s0[1]*LOG2E - mb);
      float p2 = exp2_fast(s0[2]*LOG2E - mb);
      float p3 = exp2_fast(s0[3]*LOG2E - mb);
      float p4 = exp2_fast(s1[0]*LOG2E - mb);
      float p5 = exp2_fast(s1[1]*LOG2E - mb);
      float p6 = exp2_fast(s1[2]*LOG2E - mb);
      float p7 = exp2_fast(s1[3]*LOG2E - mb);

      float psum = ((p0+p1)+(p2+p3)) + ((p4+p5)+(p6+p7));
      psum += __shfl_xor(psum, 16);
      psum += __shfl_xor(psum, 32);
      lst[nn] += psum;

      int W0 = pk_f16(p0, p1);
      int W1 = pk_f16(p2, p3);
      int W2 = pk_f16(p4, p5);
      int W3 = pk_f16(p6, p7);

      int a0 = __shfl(W0, laneA), a1 = __shfl(W1, laneA);
      int a2 = __shfl(W2, laneA), a3 = __shfl(W3, laneA);
      int b0 = __shfl(W0, laneB), b1 = __shfl(W1, laneB);
      int b2 = __shfl(W2, laneB), b3 = __shfl(W3, laneB);
      int4v ti;
      ti[0] = selLow ? a0 : a2;
      ti[1] = selLow ? a1 : a3;
      ti[2] = selLow ? b0 : b2;
      ti[3] = selLow ? b1 : b3;
      pf[nn] = __builtin_bit_cast(short8, ti);   // P[n][m = g*8 + j]
    }

    // ---- PV: V read shared by both nn
    __builtin_amdgcn_s_setprio(1);
    #pragma unroll
    for (int ct = 0; ct < 16; ct++){
      short8 vf = *(const short8*)(vbuf + ct*1024 + vb);
      o_acc[0][ct] = MFMAF16(vf, pf[0], o_acc[0][ct]);
      o_acc[1][ct] = MFMAF16(vf, pf[1], o_acc[1][ct]);
    }
    __builtin_amdgcn_s_setprio(0);

    cur = nxt;
    nxt = (nxt + 1 == 3) ? 0 : nxt + 1;
  }
#undef STAGE_TILE

  // ---- epilogue: NORMALIZED partials (o/l) in output layout
  #pragma unroll
  for (int nn = 0; nn < 2; nn++){
    const int n = qbase + w*32 + nn*16 + col;
    const float rl = 1.0f / lst[nn];
    if (kvq == 0){
      #pragma unroll
      for (int ct = 0; ct < 16; ct++)
        #pragma unroll
        for (int r = 0; r < 4; r++){
          int c = ct*16 + g*4 + r;
          outp[((size_t)(b*256 + c))*4096 + n] = o_acc[nn][ct][r] * rl;
        }
    } else {
      const size_t pbase = ((size_t)((kvq-1)*1024 + b*256))*4096;
      #pragma unroll
      for (int ct = 0; ct < 16; ct++)
        #pragma unroll
        for (int r = 0; r < 4; r++){
          int c = ct*16 + g*4 + r;
          part[pbase + (size_t)c*4096 + n] = f2h(o_acc[nn][ct][r] * rl);
        }
    }
    if (g == 0){
      const size_t mb2 = ((size_t)(kvq*4 + b)*4096 + n)*2;
      mlbuf[mb2]     = mst[nn];
      mlbuf[mb2 + 1] = lst[nn];
    }
  }
}

// ---------------------------------------------------------------- merge splits
// Partials are normalized (o/l): term_s = o_s * l_s * e^{m_s - M}.
__global__ __launch_bounds__(256) void merge_kernel(
    const unsigned short* __restrict__ part, const float* __restrict__ mlbuf,
    float* __restrict__ out, int nsplit)
{
  const int T    = blockIdx.x*256 + threadIdx.x;   // 524288
  const int rowc = T >> 9;            // b*256 + c
  const int n8   = (T & 511) * 8;
  const int b    = rowc >> 8;

  float num[8], den[8], m[8];
  {
    f32x4 a0 = *(const f32x4*)&out[(size_t)rowc*4096 + n8];
    f32x4 a1 = *(const f32x4*)&out[(size_t)rowc*4096 + n8 + 4];
    const float* mlp = &mlbuf[((size_t)b*4096 + n8)*2];
    #pragma unroll
    for (int j = 0; j < 8; j++){
      m[j]   = mlp[j*2];
      den[j] = mlp[j*2 + 1];
      num[j] = ((j < 4) ? a0[j] : a1[j-4]) * den[j];
    }
  }
  for (int s = 1; s < nsplit; s++){
    short8 pv = *(const short8*)&part[((size_t)((s-1)*1024 + rowc))*4096 + n8];
    const float* mlp = &mlbuf[((size_t)(s*4 + b)*4096 + n8)*2];
    #pragma unroll
    for (int j = 0; j < 8; j++){
      float ms = mlp[j*2], ls = mlp[j*2 + 1];
      unsigned short u = (unsigned short)pv[j];
      float ps = (float)*(const _Float16*)&u;
      float mn = fmaxf(m[j], ms);
      float sa = exp2_fast((m[j] - mn) * LOG2E);
      float sb = exp2_fast((ms   - mn) * LOG2E);
      num[j] = num[j]*sa + ps*ls*sb;
      den[j] = den[j]*sa + ls*sb;
      m[j] = mn;
    }
  }
  f32x4 o0, o1;
  #pragma unroll
  for (int j = 0; j < 8; j++){
    float v = num[j] / den[j];
    if (j < 4) o0[j] = v; else o1[j-4] = v;
  }
  float* op = out + (size_t)rowc*4096 + n8;
  *(f32x4*)op       = o0;
  *(f32x4*)(op + 4) = o1;
}

// ---------------------------------------------------------------- launch
extern "C" void kernel_launch(void* const* d_in, const int* in_sizes, int n_in,
                              void* d_out, int out_size, void* d_ws, size_t ws_size,
                              hipStream_t stream)
{
  const float* x  = (const float*)d_in[0];
  const float* y  = (const float*)d_in[1];
  const float* Wq = (const float*)d_in[2];
  const float* bq = (const float*)d_in[3];
  const float* Wk = (const float*)d_in[4];
  const float* bk = (const float*)d_in[5];
  const float* Wv = (const float*)d_in[6];
  const float* bv = (const float*)d_in[7];
  float* out = (float*)d_out;

  char* ws = (char*)d_ws;
  const size_t MB = 1048576;
  unsigned short* qf   = (unsigned short*)(ws + 0*MB);
  unsigned short* kfp  = (unsigned short*)(ws + 8*MB);
  unsigned short* vtf  = (unsigned short*)(ws + 16*MB);
  unsigned short* wf   = (unsigned short*)(ws + 24*MB);
  unsigned short* part = (unsigned short*)(ws + 24*MB + 393216);

  // split 0 partials go to d_out; ws holds (nsplit-1) f16 planes + ml.
  const int nsplit = (ws_size >= 50*MB) ? 4 : 2;
  const int iters  = (4096 / nsplit) / 32;
  float* mlb = (float*)(ws + 24*MB + 393216 + (size_t)(nsplit-1)*8*MB);

  cvt_w<<<dim3(256,3), dim3(256), 0, stream>>>(Wq, Wk, Wv, wf);
  proj_kernel<<<dim3(64,4,3), dim3(256), 0, stream>>>(x, y, wf, bq, bk, bv,
                                                      qf, kfp, vtf);
  attn_kernel<<<dim3(64*nsplit), dim3(512), 0, stream>>>(qf, kfp, vtf, out, part,
                                                         mlb, nsplit, iters);
  merge_kernel<<<dim3(2048), dim3(256), 0, stream>>>(part, mlb, out, nsplit);
}

// Round 17
// 153.465 us; speedup vs baseline: 1.1403x; 1.0059x over previous
//
#include <hip/hip_runtime.h>

// CrossAttention: B=4, C=256, H=W=64, N=4096, fp32 in/out.
// ws: qf 0 (8MB), kf 8MB, vtf 16MB, wf 24MB (384KB),
//     part f16 @24MB+384KB ((nsplit-1) x 8MB, [c][n] planes), ml f32 after.
// Split 0 partials (normalized f32) live in d_out itself ([b][c][n] layout).

typedef __attribute__((ext_vector_type(8))) short short8;
typedef __attribute__((ext_vector_type(4))) float f32x4;
typedef __attribute__((ext_vector_type(4))) int int4v;
typedef __attribute__((ext_vector_type(8))) _Float16 half8;

#define LOG2E 1.44269504089f

static __device__ __forceinline__ float exp2_fast(float x){ return __builtin_amdgcn_exp2f(x); }

static __device__ __forceinline__ int pk_f16(float a, float b){
  auto h = __builtin_amdgcn_cvt_pkrtz(a, b);   // low=a, high=b
  return __builtin_bit_cast(int, h);
}
static __device__ __forceinline__ unsigned short f2h(float v){
  return __builtin_bit_cast(unsigned short, (_Float16)v);
}

#define GLOAD16(gp, lp) __builtin_amdgcn_global_load_lds( \
  (const __attribute__((address_space(1))) void*)(gp),    \
  (__attribute__((address_space(3))) void*)(lp), 16, 0, 0)

#define MFMAF16(a,b,c) __builtin_amdgcn_mfma_f32_16x16x32_f16( \
  __builtin_bit_cast(half8, a), __builtin_bit_cast(half8, b), c, 0, 0, 0)

// ---------------------------------------------------------------- W -> f16
__global__ __launch_bounds__(256) void cvt_w(
    const float* __restrict__ wq, const float* __restrict__ wk,
    const float* __restrict__ wv, unsigned short* __restrict__ wf)
{
  const int o = blockIdx.x, t = blockIdx.y, c = threadIdx.x;
  const float* w = (t == 0) ? wq : ((t == 1) ? wk : wv);
  wf[t*65536 + o*256 + c] = f2h(w[o*256 + c]);
}

// ---------------------------------------------------------------- projections (f16 MFMA)
// LDS union: 64KB smem = xs (f32 x-tile, dead after fragment build) REUSED as
// 3x8KB W ring -> 2 blocks/CU AND counted-vmcnt W streaming (no full drains).
// All 16 ot-accumulators in registers; stores once after the loop.
__global__ __launch_bounds__(256, 2) void proj_kernel(
    const float* __restrict__ x, const float* __restrict__ y,
    const unsigned short* __restrict__ wf,
    const float* __restrict__ bq, const float* __restrict__ bk, const float* __restrict__ bv,
    unsigned short* __restrict__ qf, unsigned short* __restrict__ kf,
    unsigned short* __restrict__ vtf)
{
  __shared__ char smem[65536];          // xs (64KB f32) / wlds (3 x 8KB) union
  float* xs = (float*)smem;

  const int t   = blockIdx.z;
  const int b   = blockIdx.y;
  const int n0  = blockIdx.x * 64;
  const int tid = threadIdx.x;
  const int w   = tid >> 6, lane = tid & 63, g = lane >> 4, l15 = lane & 15;

  const float* src = ((t == 0) ? x : y) + (size_t)b*1048576 + n0;
  const char*  wt_b = (const char*)(wf + t*65536);

  int wsrc[2];
  #pragma unroll
  for (int i = 0; i < 2; i++){
    int s = w*2 + i;
    int row = s*2 + (lane >> 5);
    wsrc[i] = row*512 + (((lane & 31)*16) ^ ((row & 7) << 4));
  }

  // ---- stage x-tile (rotated rows), 64KB
  #pragma unroll
  for (int i = 0; i < 16; i++){
    int c  = i*16 + (tid >> 4);
    int gg = (c >> 3) & 3;
    int sg = ((tid & 15) - 4*gg) & 15;
    GLOAD16((const char*)src + (size_t)c*16384 + sg*16,
            (char*)xs + (i*256 + tid)*16);
  }
  __syncthreads();   // x staged (full drain)

  // ---- x^T fragments (xs is DEAD after this)
  int4v xf[8];
  {
    const int nn = (w*16 + l15 + 16*g) & 63;
    #pragma unroll
    for (int cs = 0; cs < 8; cs++){
      float v[8];
      #pragma unroll
      for (int j = 0; j < 8; j++) v[j] = xs[(cs*32 + g*8 + j)*64 + nn];
      int4v f;
      f[0] = pk_f16(v[0], v[1]); f[1] = pk_f16(v[2], v[3]);
      f[2] = pk_f16(v[4], v[5]); f[3] = pk_f16(v[6], v[7]);
      xf[cs] = f;
    }
  }
  __syncthreads();   // ALL waves done reading xs -> smem reusable for W ring

#define STAGE_W(T, BSEL) do {                                        \
    _Pragma("unroll")                                                \
    for (int i_ = 0; i_ < 2; i_++){                                  \
      int s_ = w*2 + i_;                                             \
      GLOAD16(wt_b + (size_t)(T)*8192 + wsrc[i_],                    \
              smem + (BSEL)*8192 + s_*1024);                         \
    }                                                                \
  } while (0)

  // prologue: W tile 0 into ring buf 0
  STAGE_W(0, 0);

  const float* bias = (t == 0) ? bq : ((t == 1) ? bk : bv);

  f32x4 acc[16];
  #pragma unroll
  for (int ot = 0; ot < 16; ot++){
    if (ot < 15){
      STAGE_W(ot + 1, (ot + 1) % 3);                     // issued BEFORE wait
      asm volatile("s_waitcnt vmcnt(2)" ::: "memory");   // tile ot landed
    } else {
      asm volatile("s_waitcnt vmcnt(0)" ::: "memory");
    }
    __builtin_amdgcn_s_barrier();
    __builtin_amdgcn_sched_barrier(0);

    f32x4 a;
    if (t < 2){
      float bo = bias[ot*16 + l15];
      a = (f32x4){bo, bo, bo, bo};
    } else {
      a = *(const f32x4*)&bias[ot*16 + g*4];
    }
    const char* wb = smem + (ot % 3)*8192;
    #pragma unroll
    for (int cs = 0; cs < 8; cs++){
      short8 wfr = *(const short8*)(wb + (l15*512 + ((cs*64 + g*16) ^ ((l15 & 7) << 4))));
      if (t < 2) a = MFMAF16(__builtin_bit_cast(short8, xf[cs]), wfr, a);  // D[n][o]
      else       a = MFMAF16(wfr, __builtin_bit_cast(short8, xf[cs]), a);  // D[o][n]
    }
    acc[ot] = a;
  }
#undef STAGE_W

  // epilogue: all stores once
  if (t < 2){
    unsigned short* outp = (t == 0) ? qf : kf;
    #pragma unroll
    for (int ot = 0; ot < 16; ot++)
      #pragma unroll
      for (int r = 0; r < 4; r++){
        int n = n0 + w*16 + g*4 + r;
        outp[((size_t)(b*4096 + n))*256 + ot*16 + l15] = f2h(acc[ot][r]);
      }
  } else {
    #pragma unroll
    for (int ot = 0; ot < 16; ot++)
      #pragma unroll
      for (int r = 0; r < 4; r++){
        int o = ot*16 + g*4 + r;
        vtf[((size_t)(b*256 + o))*4096 + n0 + w*16 + l15] = f2h(acc[ot][r]);
      }
  }
}

// ---------------------------------------------------------------- attention (partials)
// r10 structure (best measured): 8 waves x 32 q-rows = 256 q-rows, KV stream
// 4096/nsplit rows, KVBLK=32, TRIPLE-buffered LDS (96KB), counted vmcnt(4),
// stage-before-wait. Defer-max (THR=8); normalized f16 partials.
__global__ __launch_bounds__(512, 1) void attn_kernel(
    const unsigned short* __restrict__ qf, const unsigned short* __restrict__ kf,
    const unsigned short* __restrict__ vtf,
    float* __restrict__ outp, unsigned short* __restrict__ part,
    float* __restrict__ mlbuf, int nsplit, int iters)
{
  __shared__ short k_s[3*32*256];   // [buf][m][c], rows 512B, swz ^((m&7)<<4)
  __shared__ short v_s[3*256*32];   // [buf][c][m], rows 64B,  swz ^(((c>>1)&3)<<4)

  const int tid  = threadIdx.x;
  const int w    = tid >> 6, lane = tid & 63, g = lane >> 4, col = lane & 15;
  const int bid  = blockIdx.x;

  int b, kvq, qt;
  if (nsplit == 4){
    int xcd = bid & 7, s = bid >> 3;
    int combo = xcd*2 + (s >> 4);
    qt = s & 15;  b = combo >> 2;  kvq = combo & 3;
  } else {
    int combo = bid & 7;
    qt = bid >> 3;  b = combo >> 1;  kvq = combo & 1;
  }
  const int qbase = qt * 256;

  // Q fragments: nn in {0,1}; n = qbase + w*32 + nn*16 + col
  short8 qh[2][8];
  #pragma unroll
  for (int nn = 0; nn < 2; nn++){
    const size_t qoff = ((size_t)(b*4096 + qbase + w*32 + nn*16 + col))*256 + g*8;
    #pragma unroll
    for (int ch = 0; ch < 8; ch++)
      qh[nn][ch] = *(const short8*)(qf + qoff + ch*32);
  }

  f32x4 o_acc[2][16];
  #pragma unroll
  for (int nn = 0; nn < 2; nn++)
    #pragma unroll
    for (int i = 0; i < 16; i++){
      o_acc[nn][i][0]=0.f; o_acc[nn][i][1]=0.f; o_acc[nn][i][2]=0.f; o_acc[nn][i][3]=0.f;
    }
  float mst[2] = {-1e30f, -1e30f};
  float lst[2] = {0.f, 0.f};

  const int swzK = (col & 7) << 4;
  const int g16  = g << 4;
  const int kb0  = col * 512;
  const int kb1  = kb0 + 8192;
  const int vb   = col*64 + (g16 ^ (((col>>1)&3)<<4));

  const int laneA  = col + ((g & 1) ? 32 : 0);
  const int laneB  = laneA + 16;
  const bool selLow = (g < 2);

  int ksrc[2], vsrc[2];
  #pragma unroll
  for (int i = 0; i < 2; i++){
    int s = w*2 + i;
    int m = s*2 + (lane >> 5);
    ksrc[i] = m*512 + (((lane & 31)*16) ^ ((m & 7) << 4));
    int c = s*16 + (lane >> 2);
    vsrc[i] = c*8192 + (((lane & 3)*16) ^ (((lane >> 3) & 3) << 4));
  }

  const int rows = 4096 / nsplit;
  const char* khg = (const char*)(kf + ((size_t)b*4096 + kvq*rows)*256);
  const char* vg  = (const char*)(vtf + ((size_t)b*256)*4096) + kvq*rows*2;

#define STAGE_TILE(T, BSEL) do {                                   \
    const char* kht_ = khg + (size_t)(T)*16384;                    \
    const char* vtt_ = vg  + (size_t)(T)*64;                       \
    const int off_ = (BSEL)*16384;                                 \
    _Pragma("unroll")                                              \
    for (int i_ = 0; i_ < 2; i_++){                                \
      int s_ = w*2 + i_;                                           \
      GLOAD16(kht_ + ksrc[i_], (char*)k_s + off_ + s_*1024);       \
      GLOAD16(vtt_ + vsrc[i_], (char*)v_s + off_ + s_*1024);       \
    }                                                              \
  } while (0)

  // prologue: stage tile 0 into buf 0
  STAGE_TILE(0, 0);

  int cur = 0, nxt = 1;
  for (int it = 0; it < iters; ++it){
    if (it + 1 < iters){
      STAGE_TILE(it + 1, nxt);                           // issued BEFORE wait
      asm volatile("s_waitcnt vmcnt(4)" ::: "memory");   // tile `it` landed
    } else {
      asm volatile("s_waitcnt vmcnt(0)" ::: "memory");
    }
    __builtin_amdgcn_s_barrier();
    __builtin_amdgcn_sched_barrier(0);

    const char* kb   = (const char*)k_s + cur*16384;
    const char* vbuf = (const char*)v_s + cur*16384;

    // ---- QK^T (swapped): K read shared by both q-frags
    f32x4 s00 = {0.f,0.f,0.f,0.f}, s01 = {0.f,0.f,0.f,0.f};
    f32x4 s10 = {0.f,0.f,0.f,0.f}, s11 = {0.f,0.f,0.f,0.f};
    __builtin_amdgcn_s_setprio(1);
    #pragma unroll
    for (int ch = 0; ch < 8; ch++){
      int inr = ((ch << 6) | g16) ^ swzK;
      short8 kh0 = *(const short8*)(kb + kb0 + inr);
      short8 kh1 = *(const short8*)(kb + kb1 + inr);
      s00 = MFMAF16(kh0, qh[0][ch], s00);
      s01 = MFMAF16(kh1, qh[0][ch], s01);
      s10 = MFMAF16(kh0, qh[1][ch], s10);
      s11 = MFMAF16(kh1, qh[1][ch], s11);
    }
    __builtin_amdgcn_s_setprio(0);

    // ---- online softmax (defer-max THR=8) + P-frag per nn
    short8 pf[2];
    #pragma unroll
    for (int nn = 0; nn < 2; nn++){
      f32x4 s0 = nn ? s10 : s00;
      f32x4 s1 = nn ? s11 : s01;
      float tmax = fmaxf(fmaxf(fmaxf(s0[0],s0[1]), fmaxf(s0[2],s0[3])),
                         fmaxf(fmaxf(s1[0],s1[1]), fmaxf(s1[2],s1[3])));
      tmax = fmaxf(tmax, __shfl_xor(tmax, 16));
      tmax = fmaxf(tmax, __shfl_xor(tmax, 32));

      if (__any(tmax > mst[nn] + 8.f)){   // defer: P <= e^8, f16-safe
        float mn = fmaxf(mst[nn], tmax);
        float sc = exp2_fast((mst[nn] - mn) * LOG2E);
        lst[nn] *= sc;
        #pragma unroll
        for (int i = 0; i < 16; i++){
          o_acc[nn][i][0]*=sc; o_acc[nn][i][1]*=sc;
          o_acc[nn][i][2]*=sc; o_acc[nn][i][3]*=sc;
        }
        mst[nn] = mn;
      }
      const float mb = mst[nn] * LOG2E;
      float p0 = exp2_fast(s0[0]*LOG2E - mb);
      float p1 = exp2_fast(s0[1]*LOG2E - mb);
      float p2 = exp2_fast(s0[2]*LOG2E - mb);
      float p3 = exp2_fast(s0[3]*LOG2E - mb);
      float p4 = exp2_fast(s1[0]*LOG2E - mb);
      float p5 = exp2_fast(s1[1]*LOG2E - mb);
      float p6 = exp2_fast(s1[2]*LOG2E - mb);
      float p7 = exp2_fast(s1[3]*LOG2E - mb);

      float psum = ((p0+p1)+(p2+p3)) + ((p4+p5)+(p6+p7));
      psum += __shfl_xor(psum, 16);
      psum += __shfl_xor(psum, 32);
      lst[nn] += psum;

      int W0 = pk_f16(p0, p1);
      int W1 = pk_f16(p2, p3);
      int W2 = pk_f16(p4, p5);
      int W3 = pk_f16(p6, p7);

      int a0 = __shfl(W0, laneA), a1 = __shfl(W1, laneA);
      int a2 = __shfl(W2, laneA), a3 = __shfl(W3, laneA);
      int b0 = __shfl(W0, laneB), b1 = __shfl(W1, laneB);
      int b2 = __shfl(W2, laneB), b3 = __shfl(W3, laneB);
      int4v ti;
      ti[0] = selLow ? a0 : a2;
      ti[1] = selLow ? a1 : a3;
      ti[2] = selLow ? b0 : b2;
      ti[3] = selLow ? b1 : b3;
      pf[nn] = __builtin_bit_cast(short8, ti);   // P[n][m = g*8 + j]
    }

    // ---- PV: V read shared by both nn
    __builtin_amdgcn_s_setprio(1);
    #pragma unroll
    for (int ct = 0; ct < 16; ct++){
      short8 vf = *(const short8*)(vbuf + ct*1024 + vb);
      o_acc[0][ct] = MFMAF16(vf, pf[0], o_acc[0][ct]);
      o_acc[1][ct] = MFMAF16(vf, pf[1], o_acc[1][ct]);
    }
    __builtin_amdgcn_s_setprio(0);

    cur = nxt;
    nxt = (nxt + 1 == 3) ? 0 : nxt + 1;
  }
#undef STAGE_TILE

  // ---- epilogue: NORMALIZED partials (o/l) in output layout
  #pragma unroll
  for (int nn = 0; nn < 2; nn++){
    const int n = qbase + w*32 + nn*16 + col;
    const float rl = 1.0f / lst[nn];
    if (kvq == 0){
      #pragma unroll
      for (int ct = 0; ct < 16; ct++)
        #pragma unroll
        for (int r = 0; r < 4; r++){
          int c = ct*16 + g*4 + r;
          outp[((size_t)(b*256 + c))*4096 + n] = o_acc[nn][ct][r] * rl;
        }
    } else {
      const size_t pbase = ((size_t)((kvq-1)*1024 + b*256))*4096;
      #pragma unroll
      for (int ct = 0; ct < 16; ct++)
        #pragma unroll
        for (int r = 0; r < 4; r++){
          int c = ct*16 + g*4 + r;
          part[pbase + (size_t)c*4096 + n] = f2h(o_acc[nn][ct][r] * rl);
        }
    }
    if (g == 0){
      const size_t mb2 = ((size_t)(kvq*4 + b)*4096 + n)*2;
      mlbuf[mb2]     = mst[nn];
      mlbuf[mb2 + 1] = lst[nn];
    }
  }
}

// ---------------------------------------------------------------- merge splits
// Partials are normalized (o/l): term_s = o_s * l_s * e^{m_s - M}.
__global__ __launch_bounds__(256) void merge_kernel(
    const unsigned short* __restrict__ part, const float* __restrict__ mlbuf,
    float* __restrict__ out, int nsplit)
{
  const int T    = blockIdx.x*256 + threadIdx.x;   // 524288
  const int rowc = T >> 9;            // b*256 + c
  const int n8   = (T & 511) * 8;
  const int b    = rowc >> 8;

  float num[8], den[8], m[8];
  {
    f32x4 a0 = *(const f32x4*)&out[(size_t)rowc*4096 + n8];
    f32x4 a1 = *(const f32x4*)&out[(size_t)rowc*4096 + n8 + 4];
    const float* mlp = &mlbuf[((size_t)b*4096 + n8)*2];
    #pragma unroll
    for (int j = 0; j < 8; j++){
      m[j]   = mlp[j*2];
      den[j] = mlp[j*2 + 1];
      num[j] = ((j < 4) ? a0[j] : a1[j-4]) * den[j];
    }
  }
  for (int s = 1; s < nsplit; s++){
    short8 pv = *(const short8*)&part[((size_t)((s-1)*1024 + rowc))*4096 + n8];
    const float* mlp = &mlbuf[((size_t)(s*4 + b)*4096 + n8)*2];
    #pragma unroll
    for (int j = 0; j < 8; j++){
      float ms = mlp[j*2], ls = mlp[j*2 + 1];
      unsigned short u = (unsigned short)pv[j];
      float ps = (float)*(const _Float16*)&u;
      float mn = fmaxf(m[j], ms);
      float sa = exp2_fast((m[j] - mn) * LOG2E);
      float sb = exp2_fast((ms   - mn) * LOG2E);
      num[j] = num[j]*sa + ps*ls*sb;
      den[j] = den[j]*sa + ls*sb;
      m[j] = mn;
    }
  }
  f32x4 o0, o1;
  #pragma unroll
  for (int j = 0; j < 8; j++){
    float v = num[j] / den[j];
    if (j < 4) o0[j] = v; else o1[j-4] = v;
  }
  float* op = out + (size_t)rowc*4096 + n8;
  *(f32x4*)op       = o0;
  *(f32x4*)(op + 4) = o1;
}

// ---------------------------------------------------------------- launch
extern "C" void kernel_launch(void* const* d_in, const int* in_sizes, int n_in,
                              void* d_out, int out_size, void* d_ws, size_t ws_size,
                              hipStream_t stream)
{
  const float* x  = (const float*)d_in[0];
  const float* y  = (const float*)d_in[1];
  const float* Wq = (const float*)d_in[2];
  const float* bq = (const float*)d_in[3];
  const float* Wk = (const float*)d_in[4];
  const float* bk = (const float*)d_in[5];
  const float* Wv = (const float*)d_in[6];
  const float* bv = (const float*)d_in[7];
  float* out = (float*)d_out;

  char* ws = (char*)d_ws;
  const size_t MB = 1048576;
  unsigned short* qf   = (unsigned short*)(ws + 0*MB);
  unsigned short* kfp  = (unsigned short*)(ws + 8*MB);
  unsigned short* vtf  = (unsigned short*)(ws + 16*MB);
  unsigned short* wf   = (unsigned short*)(ws + 24*MB);
  unsigned short* part = (unsigned short*)(ws + 24*MB + 393216);

  // split 0 partials go to d_out; ws holds (nsplit-1) f16 planes + ml.
  const int nsplit = (ws_size >= 50*MB) ? 4 : 2;
  const int iters  = (4096 / nsplit) / 32;
  float* mlb = (float*)(ws + 24*MB + 393216 + (size_t)(nsplit-1)*8*MB);

  cvt_w<<<dim3(256,3), dim3(256), 0, stream>>>(Wq, Wk, Wv, wf);
  proj_kernel<<<dim3(64,4,3), dim3(256), 0, stream>>>(x, y, wf, bq, bk, bv,
                                                      qf, kfp, vtf);
  attn_kernel<<<dim3(64*nsplit), dim3(512), 0, stream>>>(qf, kfp, vtf, out, part,
                                                         mlb, nsplit, iters);
  merge_kernel<<<dim3(2048), dim3(256), 0, stream>>>(part, mlb, out, nsplit);
}

// Round 18
// 142.885 us; speedup vs baseline: 1.2247x; 1.0740x over previous
//
#include <hip/hip_runtime.h>

// CrossAttention: B=4, C=256, H=W=64, N=4096, fp32 in/out.
// ws: qf 0 (8MB), kf 8MB, vtf 16MB, wf 24MB (384KB),
//     part f16 @24MB+384KB ((nsplit-1) x 8MB, [c][n] planes), ml f32 after.
// Split 0 partials (normalized f32) live in d_out itself ([b][c][n] layout).

typedef __attribute__((ext_vector_type(8))) short short8;
typedef __attribute__((ext_vector_type(4))) float f32x4;
typedef __attribute__((ext_vector_type(4))) int int4v;
typedef __attribute__((ext_vector_type(8))) _Float16 half8;

#define LOG2E 1.44269504089f

static __device__ __forceinline__ float exp2_fast(float x){ return __builtin_amdgcn_exp2f(x); }

static __device__ __forceinline__ int pk_f16(float a, float b){
  auto h = __builtin_amdgcn_cvt_pkrtz(a, b);   // low=a, high=b
  return __builtin_bit_cast(int, h);
}
static __device__ __forceinline__ unsigned short f2h(float v){
  return __builtin_bit_cast(unsigned short, (_Float16)v);
}

#define GLOAD16(gp, lp) __builtin_amdgcn_global_load_lds( \
  (const __attribute__((address_space(1))) void*)(gp),    \
  (__attribute__((address_space(3))) void*)(lp), 16, 0, 0)

#define MFMAF16(a,b,c) __builtin_amdgcn_mfma_f32_16x16x32_f16( \
  __builtin_bit_cast(half8, a), __builtin_bit_cast(half8, b), c, 0, 0, 0)

// ---------------------------------------------------------------- W -> f16
__global__ __launch_bounds__(256) void cvt_w(
    const float* __restrict__ wq, const float* __restrict__ wk,
    const float* __restrict__ wv, unsigned short* __restrict__ wf)
{
  const int o = blockIdx.x, t = blockIdx.y, c = threadIdx.x;
  const float* w = (t == 0) ? wq : ((t == 1) ? wk : wv);
  wf[t*65536 + o*256 + c] = f2h(w[o*256 + c]);
}

// ---------------------------------------------------------------- projections (f16 MFMA)
// x^T fragments via DIRECT global loads (x/y are L3-resident; no LDS staging,
// no scalar ds_reads, one less barrier). LDS = 24KB W ring only ->
// launch_bounds(256,4): 4 blocks/CU, 2x latency hiding for W loop.
__global__ __launch_bounds__(256, 4) void proj_kernel(
    const float* __restrict__ x, const float* __restrict__ y,
    const unsigned short* __restrict__ wf,
    const float* __restrict__ bq, const float* __restrict__ bk, const float* __restrict__ bv,
    unsigned short* __restrict__ qf, unsigned short* __restrict__ kf,
    unsigned short* __restrict__ vtf)
{
  __shared__ short wlds[3][4096];    // 3 x 8KB W ring

  const int t   = blockIdx.z;
  const int b   = blockIdx.y;
  const int n0  = blockIdx.x * 64;
  const int tid = threadIdx.x;
  const int w   = tid >> 6, lane = tid & 63, g = lane >> 4, l15 = lane & 15;

  const float* src = ((t == 0) ? x : y) + (size_t)b*1048576 + n0;
  const char*  wt_b = (const char*)(wf + t*65536);

  int wsrc[2];
  #pragma unroll
  for (int i = 0; i < 2; i++){
    int s = w*2 + i;
    int row = s*2 + (lane >> 5);
    wsrc[i] = row*512 + (((lane & 31)*16) ^ ((row & 7) << 4));
  }

  // ---- x^T fragments: direct global loads, column n = n0 + w*16 + l15
  const float* xb = src + (w*16 + l15);
  int4v xf[8];
  #pragma unroll
  for (int cs = 0; cs < 8; cs++){
    float v[8];
    #pragma unroll
    for (int j = 0; j < 8; j++)
      v[j] = xb[(size_t)(cs*32 + g*8 + j)*4096];
    int4v f;
    f[0] = pk_f16(v[0], v[1]); f[1] = pk_f16(v[2], v[3]);
    f[2] = pk_f16(v[4], v[5]); f[3] = pk_f16(v[6], v[7]);
    xf[cs] = f;
  }
  // xf fully built here -> no x loads outstanding past this point

#define STAGE_W(T, BSEL) do {                                        \
    _Pragma("unroll")                                                \
    for (int i_ = 0; i_ < 2; i_++){                                  \
      int s_ = w*2 + i_;                                             \
      GLOAD16(wt_b + (size_t)(T)*8192 + wsrc[i_],                    \
              (char*)&wlds[0][0] + (BSEL)*8192 + s_*1024);           \
    }                                                                \
  } while (0)

  // prologue: W tile 0 into ring buf 0
  STAGE_W(0, 0);

  const float* bias = (t == 0) ? bq : ((t == 1) ? bk : bv);

  f32x4 acc[16];
  #pragma unroll
  for (int ot = 0; ot < 16; ot++){
    if (ot < 15){
      STAGE_W(ot + 1, (ot + 1) % 3);                     // issued BEFORE wait
      asm volatile("s_waitcnt vmcnt(2)" ::: "memory");   // tile ot landed
    } else {
      asm volatile("s_waitcnt vmcnt(0)" ::: "memory");
    }
    __builtin_amdgcn_s_barrier();
    __builtin_amdgcn_sched_barrier(0);

    f32x4 a;
    if (t < 2){
      float bo = bias[ot*16 + l15];
      a = (f32x4){bo, bo, bo, bo};
    } else {
      a = *(const f32x4*)&bias[ot*16 + g*4];
    }
    const char* wb = (const char*)&wlds[0][0] + (ot % 3)*8192;
    #pragma unroll
    for (int cs = 0; cs < 8; cs++){
      short8 wfr = *(const short8*)(wb + (l15*512 + ((cs*64 + g*16) ^ ((l15 & 7) << 4))));
      if (t < 2) a = MFMAF16(__builtin_bit_cast(short8, xf[cs]), wfr, a);  // D[n][o]
      else       a = MFMAF16(wfr, __builtin_bit_cast(short8, xf[cs]), a);  // D[o][n]
    }
    acc[ot] = a;
  }
#undef STAGE_W

  // epilogue: all stores once
  if (t < 2){
    unsigned short* outp = (t == 0) ? qf : kf;
    #pragma unroll
    for (int ot = 0; ot < 16; ot++)
      #pragma unroll
      for (int r = 0; r < 4; r++){
        int n = n0 + w*16 + g*4 + r;
        outp[((size_t)(b*4096 + n))*256 + ot*16 + l15] = f2h(acc[ot][r]);
      }
  } else {
    #pragma unroll
    for (int ot = 0; ot < 16; ot++)
      #pragma unroll
      for (int r = 0; r < 4; r++){
        int o = ot*16 + g*4 + r;
        vtf[((size_t)(b*256 + o))*4096 + n0 + w*16 + l15] = f2h(acc[ot][r]);
      }
  }
}

// ---------------------------------------------------------------- attention (partials)
// r10 structure (best measured): 8 waves x 32 q-rows = 256 q-rows, KV stream
// 4096/nsplit rows, KVBLK=32, TRIPLE-buffered LDS (96KB), counted vmcnt(4),
// stage-before-wait. Defer-max (THR=8); normalized f16 partials.
__global__ __launch_bounds__(512, 1) void attn_kernel(
    const unsigned short* __restrict__ qf, const unsigned short* __restrict__ kf,
    const unsigned short* __restrict__ vtf,
    float* __restrict__ outp, unsigned short* __restrict__ part,
    float* __restrict__ mlbuf, int nsplit, int iters)
{
  __shared__ short k_s[3*32*256];   // [buf][m][c], rows 512B, swz ^((m&7)<<4)
  __shared__ short v_s[3*256*32];   // [buf][c][m], rows 64B,  swz ^(((c>>1)&3)<<4)

  const int tid  = threadIdx.x;
  const int w    = tid >> 6, lane = tid & 63, g = lane >> 4, col = lane & 15;
  const int bid  = blockIdx.x;

  int b, kvq, qt;
  if (nsplit == 4){
    int xcd = bid & 7, s = bid >> 3;
    int combo = xcd*2 + (s >> 4);
    qt = s & 15;  b = combo >> 2;  kvq = combo & 3;
  } else {
    int combo = bid & 7;
    qt = bid >> 3;  b = combo >> 1;  kvq = combo & 1;
  }
  const int qbase = qt * 256;

  // Q fragments: nn in {0,1}; n = qbase + w*32 + nn*16 + col
  short8 qh[2][8];
  #pragma unroll
  for (int nn = 0; nn < 2; nn++){
    const size_t qoff = ((size_t)(b*4096 + qbase + w*32 + nn*16 + col))*256 + g*8;
    #pragma unroll
    for (int ch = 0; ch < 8; ch++)
      qh[nn][ch] = *(const short8*)(qf + qoff + ch*32);
  }

  f32x4 o_acc[2][16];
  #pragma unroll
  for (int nn = 0; nn < 2; nn++)
    #pragma unroll
    for (int i = 0; i < 16; i++){
      o_acc[nn][i][0]=0.f; o_acc[nn][i][1]=0.f; o_acc[nn][i][2]=0.f; o_acc[nn][i][3]=0.f;
    }
  float mst[2] = {-1e30f, -1e30f};
  float lst[2] = {0.f, 0.f};

  const int swzK = (col & 7) << 4;
  const int g16  = g << 4;
  const int kb0  = col * 512;
  const int kb1  = kb0 + 8192;
  const int vb   = col*64 + (g16 ^ (((col>>1)&3)<<4));

  const int laneA  = col + ((g & 1) ? 32 : 0);
  const int laneB  = laneA + 16;
  const bool selLow = (g < 2);

  int ksrc[2], vsrc[2];
  #pragma unroll
  for (int i = 0; i < 2; i++){
    int s = w*2 + i;
    int m = s*2 + (lane >> 5);
    ksrc[i] = m*512 + (((lane & 31)*16) ^ ((m & 7) << 4));
    int c = s*16 + (lane >> 2);
    vsrc[i] = c*8192 + (((lane & 3)*16) ^ (((lane >> 3) & 3) << 4));
  }

  const int rows = 4096 / nsplit;
  const char* khg = (const char*)(kf + ((size_t)b*4096 + kvq*rows)*256);
  const char* vg  = (const char*)(vtf + ((size_t)b*256)*4096) + kvq*rows*2;

#define STAGE_TILE(T, BSEL) do {                                   \
    const char* kht_ = khg + (size_t)(T)*16384;                    \
    const char* vtt_ = vg  + (size_t)(T)*64;                       \
    const int off_ = (BSEL)*16384;                                 \
    _Pragma("unroll")                                              \
    for (int i_ = 0; i_ < 2; i_++){                                \
      int s_ = w*2 + i_;                                           \
      GLOAD16(kht_ + ksrc[i_], (char*)k_s + off_ + s_*1024);       \
      GLOAD16(vtt_ + vsrc[i_], (char*)v_s + off_ + s_*1024);       \
    }                                                              \
  } while (0)

  // prologue: stage tile 0 into buf 0
  STAGE_TILE(0, 0);

  int cur = 0, nxt = 1;
  for (int it = 0; it < iters; ++it){
    if (it + 1 < iters){
      STAGE_TILE(it + 1, nxt);                           // issued BEFORE wait
      asm volatile("s_waitcnt vmcnt(4)" ::: "memory");   // tile `it` landed
    } else {
      asm volatile("s_waitcnt vmcnt(0)" ::: "memory");
    }
    __builtin_amdgcn_s_barrier();
    __builtin_amdgcn_sched_barrier(0);

    const char* kb   = (const char*)k_s + cur*16384;
    const char* vbuf = (const char*)v_s + cur*16384;

    // ---- QK^T (swapped): K read shared by both q-frags
    f32x4 s00 = {0.f,0.f,0.f,0.f}, s01 = {0.f,0.f,0.f,0.f};
    f32x4 s10 = {0.f,0.f,0.f,0.f}, s11 = {0.f,0.f,0.f,0.f};
    __builtin_amdgcn_s_setprio(1);
    #pragma unroll
    for (int ch = 0; ch < 8; ch++){
      int inr = ((ch << 6) | g16) ^ swzK;
      short8 kh0 = *(const short8*)(kb + kb0 + inr);
      short8 kh1 = *(const short8*)(kb + kb1 + inr);
      s00 = MFMAF16(kh0, qh[0][ch], s00);
      s01 = MFMAF16(kh1, qh[0][ch], s01);
      s10 = MFMAF16(kh0, qh[1][ch], s10);
      s11 = MFMAF16(kh1, qh[1][ch], s11);
    }
    __builtin_amdgcn_s_setprio(0);

    // ---- online softmax (defer-max THR=8) + P-frag per nn
    short8 pf[2];
    #pragma unroll
    for (int nn = 0; nn < 2; nn++){
      f32x4 s0 = nn ? s10 : s00;
      f32x4 s1 = nn ? s11 : s01;
      float tmax = fmaxf(fmaxf(fmaxf(s0[0],s0[1]), fmaxf(s0[2],s0[3])),
                         fmaxf(fmaxf(s1[0],s1[1]), fmaxf(s1[2],s1[3])));
      tmax = fmaxf(tmax, __shfl_xor(tmax, 16));
      tmax = fmaxf(tmax, __shfl_xor(tmax, 32));

      if (__any(tmax > mst[nn] + 8.f)){   // defer: P <= e^8, f16-safe
        float mn = fmaxf(mst[nn], tmax);
        float sc = exp2_fast((mst[nn] - mn) * LOG2E);
        lst[nn] *= sc;
        #pragma unroll
        for (int i = 0; i < 16; i++){
          o_acc[nn][i][0]*=sc; o_acc[nn][i][1]*=sc;
          o_acc[nn][i][2]*=sc; o_acc[nn][i][3]*=sc;
        }
        mst[nn] = mn;
      }
      const float mb = mst[nn] * LOG2E;
      float p0 = exp2_fast(s0[0]*LOG2E - mb);
      float p1 = exp2_fast(s0[1]*LOG2E - mb);
      float p2 = exp2_fast(s0[2]*LOG2E - mb);
      float p3 = exp2_fast(s0[3]*LOG2E - mb);
      float p4 = exp2_fast(s1[0]*LOG2E - mb);
      float p5 = exp2_fast(s1[1]*LOG2E - mb);
      float p6 = exp2_fast(s1[2]*LOG2E - mb);
      float p7 = exp2_fast(s1[3]*LOG2E - mb);

      float psum = ((p0+p1)+(p2+p3)) + ((p4+p5)+(p6+p7));
      psum += __shfl_xor(psum, 16);
      psum += __shfl_xor(psum, 32);
      lst[nn] += psum;

      int W0 = pk_f16(p0, p1);
      int W1 = pk_f16(p2, p3);
      int W2 = pk_f16(p4, p5);
      int W3 = pk_f16(p6, p7);

      int a0 = __shfl(W0, laneA), a1 = __shfl(W1, laneA);
      int a2 = __shfl(W2, laneA), a3 = __shfl(W3, laneA);
      int b0 = __shfl(W0, laneB), b1 = __shfl(W1, laneB);
      int b2 = __shfl(W2, laneB), b3 = __shfl(W3, laneB);
      int4v ti;
      ti[0] = selLow ? a0 : a2;
      ti[1] = selLow ? a1 : a3;
      ti[2] = selLow ? b0 : b2;
      ti[3] = selLow ? b1 : b3;
      pf[nn] = __builtin_bit_cast(short8, ti);   // P[n][m = g*8 + j]
    }

    // ---- PV: V read shared by both nn
    __builtin_amdgcn_s_setprio(1);
    #pragma unroll
    for (int ct = 0; ct < 16; ct++){
      short8 vf = *(const short8*)(vbuf + ct*1024 + vb);
      o_acc[0][ct] = MFMAF16(vf, pf[0], o_acc[0][ct]);
      o_acc[1][ct] = MFMAF16(vf, pf[1], o_acc[1][ct]);
    }
    __builtin_amdgcn_s_setprio(0);

    cur = nxt;
    nxt = (nxt + 1 == 3) ? 0 : nxt + 1;
  }
#undef STAGE_TILE

  // ---- epilogue: NORMALIZED partials (o/l) in output layout
  #pragma unroll
  for (int nn = 0; nn < 2; nn++){
    const int n = qbase + w*32 + nn*16 + col;
    const float rl = 1.0f / lst[nn];
    if (kvq == 0){
      #pragma unroll
      for (int ct = 0; ct < 16; ct++)
        #pragma unroll
        for (int r = 0; r < 4; r++){
          int c = ct*16 + g*4 + r;
          outp[((size_t)(b*256 + c))*4096 + n] = o_acc[nn][ct][r] * rl;
        }
    } else {
      const size_t pbase = ((size_t)((kvq-1)*1024 + b*256))*4096;
      #pragma unroll
      for (int ct = 0; ct < 16; ct++)
        #pragma unroll
        for (int r = 0; r < 4; r++){
          int c = ct*16 + g*4 + r;
          part[pbase + (size_t)c*4096 + n] = f2h(o_acc[nn][ct][r] * rl);
        }
    }
    if (g == 0){
      const size_t mb2 = ((size_t)(kvq*4 + b)*4096 + n)*2;
      mlbuf[mb2]     = mst[nn];
      mlbuf[mb2 + 1] = lst[nn];
    }
  }
}

// ---------------------------------------------------------------- merge splits
// Partials are normalized (o/l): term_s = o_s * l_s * e^{m_s - M}.
__global__ __launch_bounds__(256) void merge_kernel(
    const unsigned short* __restrict__ part, const float* __restrict__ mlbuf,
    float* __restrict__ out, int nsplit)
{
  const int T    = blockIdx.x*256 + threadIdx.x;   // 524288
  const int rowc = T >> 9;            // b*256 + c
  const int n8   = (T & 511) * 8;
  const int b    = rowc >> 8;

  float num[8], den[8], m[8];
  {
    f32x4 a0 = *(const f32x4*)&out[(size_t)rowc*4096 + n8];
    f32x4 a1 = *(const f32x4*)&out[(size_t)rowc*4096 + n8 + 4];
    const float* mlp = &mlbuf[((size_t)b*4096 + n8)*2];
    #pragma unroll
    for (int j = 0; j < 8; j++){
      m[j]   = mlp[j*2];
      den[j] = mlp[j*2 + 1];
      num[j] = ((j < 4) ? a0[j] : a1[j-4]) * den[j];
    }
  }
  for (int s = 1; s < nsplit; s++){
    short8 pv = *(const short8*)&part[((size_t)((s-1)*1024 + rowc))*4096 + n8];
    const float* mlp = &mlbuf[((size_t)(s*4 + b)*4096 + n8)*2];
    #pragma unroll
    for (int j = 0; j < 8; j++){
      float ms = mlp[j*2], ls = mlp[j*2 + 1];
      unsigned short u = (unsigned short)pv[j];
      float ps = (float)*(const _Float16*)&u;
      float mn = fmaxf(m[j], ms);
      float sa = exp2_fast((m[j] - mn) * LOG2E);
      float sb = exp2_fast((ms   - mn) * LOG2E);
      num[j] = num[j]*sa + ps*ls*sb;
      den[j] = den[j]*sa + ls*sb;
      m[j] = mn;
    }
  }
  f32x4 o0, o1;
  #pragma unroll
  for (int j = 0; j < 8; j++){
    float v = num[j] / den[j];
    if (j < 4) o0[j] = v; else o1[j-4] = v;
  }
  float* op = out + (size_t)rowc*4096 + n8;
  *(f32x4*)op       = o0;
  *(f32x4*)(op + 4) = o1;
}

// ---------------------------------------------------------------- launch
extern "C" void kernel_launch(void* const* d_in, const int* in_sizes, int n_in,
                              void* d_out, int out_size, void* d_ws, size_t ws_size,
                              hipStream_t stream)
{
  const float* x  = (const float*)d_in[0];
  const float* y  = (const float*)d_in[1];
  const float* Wq = (const float*)d_in[2];
  const float* bq = (const float*)d_in[3];
  const float* Wk = (const float*)d_in[4];
  const float* bk = (const float*)d_in[5];
  const float* Wv = (const float*)d_in[6];
  const float* bv = (const float*)d_in[7];
  float* out = (float*)d_out;

  char* ws = (char*)d_ws;
  const size_t MB = 1048576;
  unsigned short* qf   = (unsigned short*)(ws + 0*MB);
  unsigned short* kfp  = (unsigned short*)(ws + 8*MB);
  unsigned short* vtf  = (unsigned short*)(ws + 16*MB);
  unsigned short* wf   = (unsigned short*)(ws + 24*MB);
  unsigned short* part = (unsigned short*)(ws + 24*MB + 393216);

  // split 0 partials go to d_out; ws holds (nsplit-1) f16 planes + ml.
  const int nsplit = (ws_size >= 50*MB) ? 4 : 2;
  const int iters  = (4096 / nsplit) / 32;
  float* mlb = (float*)(ws + 24*MB + 393216 + (size_t)(nsplit-1)*8*MB);

  cvt_w<<<dim3(256,3), dim3(256), 0, stream>>>(Wq, Wk, Wv, wf);
  proj_kernel<<<dim3(64,4,3), dim3(256), 0, stream>>>(x, y, wf, bq, bk, bv,
                                                      qf, kfp, vtf);
  attn_kernel<<<dim3(64*nsplit), dim3(512), 0, stream>>>(qf, kfp, vtf, out, part,
                                                         mlb, nsplit, iters);
  merge_kernel<<<dim3(2048), dim3(256), 0, stream>>>(part, mlb, out, nsplit);
}